// Round 8
// baseline (190.106 us; speedup 1.0000x reference)
//
#include <hip/hip_runtime.h>

// Shapes (fixed): B=2, T=2048, E=1024, H=16, Hkv=4, D=64, G=4, W=1024
// Scores bounded: q rmsnormed (|q|=8) * 0.125 * k rmsnormed (|k|=8) => |s| <= 8.
// log2(e) folded into q; softmax uses exp2 with FIXED max M = 8*log2(e).
// Attention R8: HEAD-SHARED staging. One block = 64 q-rows x ALL 4 heads of
// one (b,hkv): the staged K/V tile is consumed by 4 heads' MFMA instead of 1.
// Per-CU tile-stagings drop 102 -> 34 (x3 less staging+barrier work); K/V LDS
// fragments loaded once per tile, reused 4x. 256 blocks = 1/CU; latency hidden
// by 1-tile-ahead register prefetch + 4x compute per tile. XCD-chunked bid:
// each XCD owns one (b,hkv) K/V panel (512KB, L2-resident).
// R7: XCD-aware chunked remap on both GEMMs (T1).
// R6: gemm_bf16 128x128 tile, BK=128 dbuf, 64 MFMA/barrier, 1 block/CU.
// GEMM staging: XOR-swizzled LDS 16B-groups (grp ^ row&7) -> conflict-free
// reads while keeping global_load_lds's wave-uniform-base staging.

typedef float f32x4 __attribute__((ext_vector_type(4)));
typedef short s16x8 __attribute__((ext_vector_type(8)));
typedef short s16x4 __attribute__((ext_vector_type(4)));
typedef _Float16 f16x4 __attribute__((ext_vector_type(4)));

__device__ __forceinline__ unsigned short f2bf(float f) {
  unsigned u = __float_as_uint(f);
  u += 0x7fffu + ((u >> 16) & 1u);   // RNE
  return (unsigned short)(u >> 16);
}
__device__ __forceinline__ unsigned short h16(float f) {
  _Float16 h = (_Float16)f;
  return __builtin_bit_cast(unsigned short, h);
}

__device__ __forceinline__ float fexp2(float x) {
#if __has_builtin(__builtin_amdgcn_exp2f)
  return __builtin_amdgcn_exp2f(x);
#else
  return __expf(x * 0.69314718f);
#endif
}

// async global->LDS, 16B per lane; LDS dest = wave-uniform base + lane*16
__device__ __forceinline__ void gl2lds16(const unsigned short* g, unsigned short* l) {
  __builtin_amdgcn_global_load_lds((const __attribute__((address_space(1))) unsigned int*)g,
                                   (__attribute__((address_space(3))) unsigned int*)l, 16, 0, 0);
}

// ---------------- fp32->bf16 converts + gate, one launch ----------------
__global__ __launch_bounds__(256) void cvt_gate(
    const float* __restrict__ x, const float* __restrict__ wq, const float* __restrict__ wk,
    const float* __restrict__ wv, const float* __restrict__ wp, const float* __restrict__ wgate,
    unsigned short* __restrict__ xb, unsigned short* __restrict__ wqkv,
    unsigned short* __restrict__ wpj, float* __restrict__ gatep) {
  int blk = blockIdx.x;
  if (blk < 6656) {
    int i = blk * 256 + threadIdx.x;  // float4 index, total 1703936
    const float* s;
    unsigned short* d;
    if (i < 1048576) { s = x; d = xb; }
    else if (i < 1310720) { i -= 1048576; s = wq; d = wqkv; }
    else if (i < 1376256) { i -= 1310720; s = wk; d = wqkv + 1048576; }
    else if (i < 1441792) { i -= 1376256; s = wv; d = wqkv + 1310720; }
    else { i -= 1441792; s = wp; d = wpj; }
    float4 v = ((const float4*)s)[i];
    ushort4 o;
    o.x = f2bf(v.x); o.y = f2bf(v.y); o.z = f2bf(v.z); o.w = f2bf(v.w);
    ((ushort4*)d)[i] = o;
  } else {
    int i = (blk - 6656) * 256 + threadIdx.x;  // i = bt*4 + h, total 16384
    int bt = i >> 2, h = i & 3;
    const float4* xp = (const float4*)(x + (size_t)bt * 1024);
    const float4* wpt = (const float4*)(wgate + h * 32);
    float s = 0.f;
#pragma unroll
    for (int j = 0; j < 8; ++j) {
      float4 a = xp[j], b = wpt[j];
      s += a.x * b.x + a.y * b.y + a.z * b.z + a.w * b.w;
    }
    gatep[i] = 2.f / (1.f + __expf(-s));
  }
}

// ---- fused QKV GEMM (64x128 tile, BK=128, swizzled LDS) + RoPE/RMSNorm/gate-ve ----
// A = xb (4096x1024), B = wqkv (1536x1024). Col-tile bn: 0-7 q, 8-9 k, 10-11 v.
// v-epilogue writes vp2 tiled layout directly (transpose_v fused).
__global__ __launch_bounds__(256) void gemm_qkv(
    const unsigned short* __restrict__ A, const unsigned short* __restrict__ B,
    const float* __restrict__ cosp, const float* __restrict__ sinp,
    const float* __restrict__ gatep, const float* __restrict__ ve,
    unsigned short* __restrict__ q_r, unsigned short* __restrict__ k_r,
    unsigned short* __restrict__ vp2) {
  __shared__ unsigned short smem[24576];   // As 64x128 | Bs 128x128; epilogue aliases
  unsigned short* As = smem;               // 8192 elems
  unsigned short* Bs = smem + 8192;        // 16384 elems
  const int K = 1024;
  // R7 XCD chunked remap: 768 blocks, 96/XCD; XCD x gets bm in [8x, 8x+8)
  int lin = blockIdx.y * 12 + blockIdx.x;
  int nl = (lin & 7) * 96 + (lin >> 3);
  int bn = nl % 12, bm = nl / 12;
  int t = threadIdx.x;
  int w = t >> 6, lane = t & 63;
  int c = lane & 15, g = lane >> 4;
  int wm = w >> 1, wn = w & 1;

  f32x4 acc[2][4];
#pragma unroll
  for (int i = 0; i < 2; ++i)
#pragma unroll
    for (int j = 0; j < 4; ++j) acc[i][j] = (f32x4){0.f, 0.f, 0.f, 0.f};

  const unsigned short* Ab = A + (size_t)(bm * 64) * K;
  const unsigned short* Bb = B + (size_t)(bn * 128) * K;
  int srow = lane >> 4;                         // 0..3 (4 rows of 256B per call)
  int sgrp = lane & 15;                         // 16B group within 128-elem row

  for (int k0 = 0; k0 < K; k0 += 128) {
#pragma unroll
    for (int j = 0; j < 4; ++j) {  // A rows w*16 .. +15
      int r0 = w * 16 + j * 4;
      int r = r0 + srow;
      gl2lds16(Ab + (size_t)r * K + k0 + (sgrp ^ (r & 7)) * 8, As + r0 * 128);
    }
#pragma unroll
    for (int j = 0; j < 8; ++j) {  // B rows w*32 .. +31
      int r0 = w * 32 + j * 4;
      int r = r0 + srow;
      gl2lds16(Bb + (size_t)r * K + k0 + (sgrp ^ (r & 7)) * 8, Bs + r0 * 128);
    }
    __syncthreads();
#pragma unroll
    for (int kk = 0; kk < 4; ++kk) {
      int sw = ((kk * 4 + g) ^ (c & 7)) * 8;  // row&7 == c&7 for all tiles
      s16x8 af[2], bf[4];
#pragma unroll
      for (int mt = 0; mt < 2; ++mt)
        af[mt] = *(const s16x8*)(As + (wm * 32 + mt * 16 + c) * 128 + sw);
#pragma unroll
      for (int nt = 0; nt < 4; ++nt)
        bf[nt] = *(const s16x8*)(Bs + (wn * 64 + nt * 16 + c) * 128 + sw);
#pragma unroll
      for (int mt = 0; mt < 2; ++mt)
#pragma unroll
        for (int nt = 0; nt < 4; ++nt)
          acc[mt][nt] = __builtin_amdgcn_mfma_f32_16x16x32_bf16(af[mt], bf[nt], acc[mt][nt], 0, 0, 0);
    }
    __syncthreads();
  }

  // epilogue: lane (c,g) reg r of (mt,nt): local row = wm*32+mt*16+g*4+r,
  // within-head d = nt*16 + c (head = 64 cols = wn half-tile)
  const float QSCL = 0.125f * 1.44269504f;
  if (bn < 10) {  // q/k: rope + rmsnorm -> wave-private LDS transpose -> b128 stores
    unsigned short* eb = smem + w * 2176;  // 32 x 68
#pragma unroll
    for (int mt = 0; mt < 2; ++mt) {
#pragma unroll
      for (int r = 0; r < 4; ++r) {
        int lrow = mt * 16 + g * 4 + r;
        int rowg = bm * 64 + wm * 32 + lrow;
        int tt = rowg & 2047;
        float v0 = acc[mt][0][r], v1 = acc[mt][1][r], v2 = acc[mt][2][r], v3 = acc[mt][3][r];
        float cs0 = cosp[tt * 32 + c], sn0 = sinp[tt * 32 + c];
        float cs1 = cosp[tt * 32 + 16 + c], sn1 = sinp[tt * 32 + 16 + c];
        float r0 = v0 * cs0 + v2 * sn0;
        float r1 = v1 * cs1 + v3 * sn1;
        float r2 = v2 * cs0 - v0 * sn0;
        float r3 = v3 * cs1 - v1 * sn1;
        float ss = r0 * r0 + r1 * r1 + r2 * r2 + r3 * r3;
        ss += __shfl_xor(ss, 1);
        ss += __shfl_xor(ss, 2);
        ss += __shfl_xor(ss, 4);
        ss += __shfl_xor(ss, 8);
        float sc = rsqrtf(ss * (1.0f / 64.0f) + 1.1920929e-07f);
        if (bn < 8) sc *= QSCL;
        eb[lrow * 68 + c] = f2bf(r0 * sc);
        eb[lrow * 68 + 16 + c] = f2bf(r1 * sc);
        eb[lrow * 68 + 32 + c] = f2bf(r2 * sc);
        eb[lrow * 68 + 48 + c] = f2bf(r3 * sc);
      }
    }
    asm volatile("s_waitcnt lgkmcnt(0)" ::: "memory");  // wave-private
#pragma unroll
    for (int j = 0; j < 4; ++j) {
      int idx = lane * 4 + j;  // 256 chunks: 32 rows x 8
      int lrow = idx >> 3;
      int ck = idx & 7;
      s16x8 val = *(const s16x8*)(eb + lrow * 68 + ck * 8);
      int rowg = bm * 64 + wm * 32 + lrow;
      int b = rowg >> 11, tt = rowg & 2047;
      unsigned short* dst;
      if (bn < 8) dst = q_r + ((size_t)(b * 16 + bn * 2 + wn) * 2048 + tt) * 64 + ck * 8;
      else dst = k_r + ((size_t)(b * 4 + (bn - 8) * 2 + wn) * 2048 + tt) * 64 + ck * 8;
      *(s16x8*)dst = val;
    }
  } else {  // v: + gate*ve, transpose to vp2 tiled [s][tile32][d][32keys] fp16
    unsigned short* eb = smem + w * 2560;  // 64 d x 40 (keys padded)
    int h = (bn - 10) * 2 + wn;
#pragma unroll
    for (int mt = 0; mt < 2; ++mt) {
#pragma unroll
      for (int r = 0; r < 4; ++r) {
        int key = mt * 16 + g * 4 + r;               // 0..31 within wave tile
        int rowg = bm * 64 + wm * 32 + key;
        float gate = gatep[rowg * 4 + h];
        const float* vep = ve + (size_t)rowg * 256 + h * 64;
        eb[(0 * 16 + c) * 40 + key] = h16(acc[mt][0][r] + gate * vep[c]);
        eb[(1 * 16 + c) * 40 + key] = h16(acc[mt][1][r] + gate * vep[16 + c]);
        eb[(2 * 16 + c) * 40 + key] = h16(acc[mt][2][r] + gate * vep[32 + c]);
        eb[(3 * 16 + c) * 40 + key] = h16(acc[mt][3][r] + gate * vep[48 + c]);
      }
    }
    asm volatile("s_waitcnt lgkmcnt(0)" ::: "memory");  // wave-private
    int rowg0 = bm * 64 + wm * 32;
    int b = rowg0 >> 11;
    int tile = (rowg0 & 2047) >> 5;
    unsigned short* vb = vp2 + ((size_t)(b * 4 + h) * 64 + tile) * 2048;
#pragma unroll
    for (int j = 0; j < 4; ++j) {
      int cid = j * 64 + lane;  // 256 chunks: 64 d x 4 keygroups
      int d = cid >> 2;
      int kg = cid & 3;
      s16x8 val = *(const s16x8*)(eb + d * 40 + kg * 8);
      *(s16x8*)(vb + d * 32 + kg * 8) = val;
    }
  }
}

// ------- bf16 GEMM 128x128 (m97 structure), BK=128 dbuf, C = A @ B^T -------
// 4 waves, each 64x64 output: 16 MFMA per 8 ds_reads per kk, 64 MFMA/barrier.
// Grid (N/128, M/128) = (8,32) = 256 blocks = exactly 1 block/CU.
__global__ __launch_bounds__(256) void gemm_bf16_128(
    const unsigned short* __restrict__ A, const unsigned short* __restrict__ B,
    float* __restrict__ C, int K, int ldc) {
  __shared__ unsigned short As[2][128 * 128];
  __shared__ unsigned short Bs[2][128 * 128];
  // R7 XCD chunked remap: 256 blocks, 32/XCD; XCD x gets bm in [4x, 4x+4)
  int lin = blockIdx.y * 8 + blockIdx.x;
  int nl = (lin & 7) * 32 + (lin >> 3);
  int bn = nl & 7, bm = nl >> 3;
  int t = threadIdx.x;
  int w = t >> 6, lane = t & 63;
  int c = lane & 15, g = lane >> 4;
  int wm = w >> 1, wn = w & 1;

  f32x4 acc[4][4];
#pragma unroll
  for (int i = 0; i < 4; ++i)
#pragma unroll
    for (int j = 0; j < 4; ++j) acc[i][j] = (f32x4){0.f, 0.f, 0.f, 0.f};

  const unsigned short* Ab = A + (size_t)(bm * 128) * K;
  const unsigned short* Bb = B + (size_t)(bn * 128) * K;
  int srow = lane >> 4;   // 0..3
  int sgrp = lane & 15;   // 16B group within 128-elem row

  // stage K-step k0 into buffer buf: each wave stages its 32 rows of A and B
#define STAGE128(buf, k0)                                                          \
  {                                                                                \
    _Pragma("unroll")                                                              \
    for (int j = 0; j < 8; ++j) {                                                  \
      int r0 = w * 32 + j * 4;                                                     \
      int r = r0 + srow;                                                           \
      gl2lds16(Ab + (size_t)r * K + (k0) + (sgrp ^ (r & 7)) * 8, &As[buf][r0 * 128]); \
      gl2lds16(Bb + (size_t)r * K + (k0) + (sgrp ^ (r & 7)) * 8, &Bs[buf][r0 * 128]); \
    }                                                                              \
  }

  STAGE128(0, 0);
  for (int tstep = 0; tstep < 8; ++tstep) {
    int buf = tstep & 1;
    __syncthreads();  // drains this wave's vmcnt -> buf staged; all waves synced
    if (tstep < 7) STAGE128(buf ^ 1, (tstep + 1) * 128);
#pragma unroll
    for (int kk = 0; kk < 4; ++kk) {
      int sw = ((kk * 4 + g) ^ (c & 7)) * 8;
      s16x8 af[4], bf[4];
#pragma unroll
      for (int mt = 0; mt < 4; ++mt)
        af[mt] = *(const s16x8*)(&As[buf][(wm * 64 + mt * 16 + c) * 128 + sw]);
#pragma unroll
      for (int nt = 0; nt < 4; ++nt)
        bf[nt] = *(const s16x8*)(&Bs[buf][(wn * 64 + nt * 16 + c) * 128 + sw]);
#pragma unroll
      for (int mt = 0; mt < 4; ++mt)
#pragma unroll
        for (int nt = 0; nt < 4; ++nt)
          acc[mt][nt] = __builtin_amdgcn_mfma_f32_16x16x32_bf16(af[mt], bf[nt], acc[mt][nt], 0, 0, 0);
    }
  }
#undef STAGE128

#pragma unroll
  for (int mt = 0; mt < 4; ++mt)
#pragma unroll
    for (int nt = 0; nt < 4; ++nt)
#pragma unroll
      for (int r = 0; r < 4; ++r) {
        int rowg = bm * 128 + wm * 64 + mt * 16 + g * 4 + r;
        int colg = bn * 128 + wn * 64 + nt * 16 + c;
        C[(size_t)rowg * ldc + colg] = acc[mt][nt][r];
      }
}

// ---- flash attention R8: head-shared staging. Block = 64 q-rows x 4 heads ----
// of one (b,hkv). 256 blocks = 1/CU. Stage K/V tile once; 4 heads of MFMA
// amortize it. S^T = K·Q^T; dbuf LDS; ONE barrier per 32-key tile.
__global__ __launch_bounds__(256) void attn_kernel(
    const unsigned short* __restrict__ q_r, const unsigned short* __restrict__ k_r,
    const unsigned short* __restrict__ v_p2, unsigned short* __restrict__ y_b,
    const int* __restrict__ wptr) {
  const int W = *wptr;
  const int bid0 = blockIdx.x;
  // XCD-chunked: XCD x (= bid0 & 7) owns panel (b*4+hkv) = x -> K/V L2-resident
  const int bid = (bid0 & 7) * 32 + (bid0 >> 3);
  const int qt = bid & 31;
  const int hkv = (bid >> 5) & 3;
  const int b = bid >> 7;
  const int tid = threadIdx.x;
  const int w = tid >> 6, lane = tid & 63, c = lane & 15, g = lane >> 4;
  const int r0b = qt * 64;
  const int r0w = r0b + w * 16;
  const float M = 11.5415603f;  // 8 * log2(e)

  __shared__ unsigned short Ks[2][32 * 68];
  __shared__ unsigned short Vs[2][64 * 40];

  const unsigned short* kbase = k_r + (size_t)(b * 4 + hkv) * 131072;
  const unsigned short* vbase = v_p2 + (size_t)(b * 4 + hkv) * 131072;

  // q fragments for all 4 heads of this kv-group
  s16x8 q_lo[4], q_hi[4];
#pragma unroll
  for (int hh = 0; hh < 4; ++hh) {
    const unsigned short* qbase =
        q_r + ((size_t)(b * 16 + hkv * 4 + hh) * 2048 + r0w) * 64;
    q_lo[hh] = *(const s16x8*)(qbase + c * 64 + g * 8);
    q_hi[hh] = *(const s16x8*)(qbase + c * 64 + 32 + g * 8);
  }

  int kt0w = r0w - W; if (kt0w < 0) kt0w = 0;
  const int ktEw = r0w + 16;
  int KT0 = r0b - W; if (KT0 < 0) KT0 = 0;
  KT0 &= ~31;
  const int KTE = r0b + 64;

  float l_part[4] = {0.f, 0.f, 0.f, 0.f};
  f32x4 acc[4][4];  // [head][dt]
#pragma unroll
  for (int hh = 0; hh < 4; ++hh)
#pragma unroll
    for (int dt = 0; dt < 4; ++dt) acc[hh][dt] = (f32x4){0.f, 0.f, 0.f, 0.f};

  s16x8 pk = *(const s16x8*)(kbase + (size_t)KT0 * 64 + tid * 8);
  s16x8 pv = *(const s16x8*)(vbase + (size_t)(KT0 >> 5) * 2048 + tid * 8);

  const int koff = (tid >> 3) * 68 + (tid & 7) * 8;
  const int voff = (tid >> 2) * 40 + (tid & 3) * 8;
  const int qrow = r0w + c;

  int bufI = 0;
  for (int kt = KT0; kt < KTE; kt += 32, bufI ^= 1) {
    int nkt = (kt + 32 < KTE) ? kt + 32 : kt;
    s16x8 nk = *(const s16x8*)(kbase + (size_t)nkt * 64 + tid * 8);
    s16x8 nv = *(const s16x8*)(vbase + (size_t)(nkt >> 5) * 2048 + tid * 8);

    // stage into buf bufI (other buffer may still be read by lagging waves - safe)
    unsigned short* kdst = &Ks[bufI][koff];
    *(s16x4*)kdst = __builtin_shufflevector(pk, pk, 0, 1, 2, 3);
    *(s16x4*)(kdst + 4) = __builtin_shufflevector(pk, pk, 4, 5, 6, 7);
    *(s16x8*)(&Vs[bufI][voff]) = pv;
    __syncthreads();  // the ONLY barrier per tile

    if (kt + 32 > kt0w && kt < ktEw) {
      // K fragments: loaded ONCE, reused by all 4 heads
      const unsigned short* kr0 = &Ks[bufI][c * 68 + g * 8];
      s16x4 a0 = *(const s16x4*)(kr0);
      s16x4 a1 = *(const s16x4*)(kr0 + 4);
      s16x4 a2 = *(const s16x4*)(kr0 + 32);
      s16x4 a3 = *(const s16x4*)(kr0 + 36);
      const unsigned short* kr1 = kr0 + 16 * 68;
      s16x4 a4 = *(const s16x4*)(kr1);
      s16x4 a5 = *(const s16x4*)(kr1 + 4);
      s16x4 a6 = *(const s16x4*)(kr1 + 32);
      s16x4 a7 = *(const s16x4*)(kr1 + 36);
      s16x8 k0lo = __builtin_shufflevector(a0, a1, 0, 1, 2, 3, 4, 5, 6, 7);
      s16x8 k0hi = __builtin_shufflevector(a2, a3, 0, 1, 2, 3, 4, 5, 6, 7);
      s16x8 k1lo = __builtin_shufflevector(a4, a5, 0, 1, 2, 3, 4, 5, 6, 7);
      s16x8 k1hi = __builtin_shufflevector(a6, a7, 0, 1, 2, 3, 4, 5, 6, 7);

      // V fragments: loaded ONCE, reused by all 4 heads
      f16x4 vfa[4], vfb[4];
#pragma unroll
      for (int dt = 0; dt < 4; ++dt) {
        const unsigned short* vr = &Vs[bufI][(dt * 16 + c) * 40 + g * 4];
        vfa[dt] = *(const f16x4*)(vr);
        vfb[dt] = *(const f16x4*)(vr + 16);
      }

      const bool edge = (kt < kt0w + 32) || (kt + 32 > r0w);

#pragma unroll
      for (int hh = 0; hh < 4; ++hh) {
        f32x4 S0 = (f32x4){0.f, 0.f, 0.f, 0.f};
        f32x4 S1 = (f32x4){0.f, 0.f, 0.f, 0.f};
        S0 = __builtin_amdgcn_mfma_f32_16x16x32_bf16(k0lo, q_lo[hh], S0, 0, 0, 0);
        S0 = __builtin_amdgcn_mfma_f32_16x16x32_bf16(k0hi, q_hi[hh], S0, 0, 0, 0);
        S1 = __builtin_amdgcn_mfma_f32_16x16x32_bf16(k1lo, q_lo[hh], S1, 0, 0, 0);
        S1 = __builtin_amdgcn_mfma_f32_16x16x32_bf16(k1hi, q_hi[hh], S1, 0, 0, 0);

        f16x4 P0, P1;
        float lp = 0.f;
#pragma unroll
        for (int r = 0; r < 4; ++r) {
          float p0 = fexp2(S0[r] - M);
          float p1 = fexp2(S1[r] - M);
          if (edge) {
            int k0i = kt + g * 4 + r;
            int k1i = k0i + 16;
            if (!(k0i <= qrow && k0i >= qrow - W)) p0 = 0.f;
            if (!(k1i <= qrow && k1i >= qrow - W)) p1 = 0.f;
          }
          lp += p0 + p1;
          P0[r] = (_Float16)p0;
          P1[r] = (_Float16)p1;
        }
        l_part[hh] += lp;

#pragma unroll
        for (int dt = 0; dt < 4; ++dt) {
          acc[hh][dt] = __builtin_amdgcn_mfma_f32_16x16x16f16(vfa[dt], P0, acc[hh][dt], 0, 0, 0);
          acc[hh][dt] = __builtin_amdgcn_mfma_f32_16x16x16f16(vfb[dt], P1, acc[hh][dt], 0, 0, 0);
        }
      }
    }
    pk = nk; pv = nv;
  }

#pragma unroll
  for (int hh = 0; hh < 4; ++hh) {
    float l = l_part[hh];
    l += __shfl_xor(l, 16);
    l += __shfl_xor(l, 32);
    float inv = 1.0f / l;
    unsigned short* ob =
        y_b + ((size_t)(b * 2048 + r0w + c) * 16 + hkv * 4 + hh) * 64 + g * 4;
#pragma unroll
    for (int dt = 0; dt < 4; ++dt) {
      ushort4 o;
      o.x = f2bf(acc[hh][dt][0] * inv);
      o.y = f2bf(acc[hh][dt][1] * inv);
      o.z = f2bf(acc[hh][dt][2] * inv);
      o.w = f2bf(acc[hh][dt][3] * inv);
      *(ushort4*)(ob + dt * 16) = o;
    }
  }
}

extern "C" void kernel_launch(void* const* d_in, const int* in_sizes, int n_in,
                              void* d_out, int out_size, void* d_ws, size_t ws_size,
                              hipStream_t stream) {
  const float* x = (const float*)d_in[0];
  const float* ve = (const float*)d_in[1];
  const float* cosp = (const float*)d_in[2];
  const float* sinp = (const float*)d_in[3];
  const float* Wq = (const float*)d_in[4];
  const float* Wk = (const float*)d_in[5];
  const float* Wv = (const float*)d_in[6];
  const float* Wproj = (const float*)d_in[7];
  const float* Wgate = (const float*)d_in[8];
  const int* wptr = (const int*)d_in[9];

  unsigned short* xb = (unsigned short*)d_ws;        // 4096x1024 bf16
  unsigned short* wqkv = xb + 4194304;               // 1536x1024 bf16
  unsigned short* wpj = wqkv + 1572864;              // 1024x1024 bf16
  unsigned short* q_r = wpj + 1048576;               // [B,H,T,D] bf16
  unsigned short* k_r = q_r + 4194304;               // [B,Hkv,T,D] bf16
  unsigned short* y_b = k_r + 1048576;               // [B,T,H,D] bf16
  unsigned short* vp2 = y_b + 4194304;               // [B*Hkv][T/32][64][32] fp16
  float* gatep = (float*)(vp2 + 1048576);            // [4096][4] fp32

  cvt_gate<<<6720, 256, 0, stream>>>(x, Wq, Wk, Wv, Wproj, Wgate, xb, wqkv, wpj, gatep);
  gemm_qkv<<<dim3(12, 64), 256, 0, stream>>>(xb, wqkv, cosp, sinp, gatep, ve, q_r, k_r, vp2);
  attn_kernel<<<256, 256, 0, stream>>>(q_r, k_r, vp2, y_b, wptr);
  gemm_bf16_128<<<dim3(8, 32), 256, 0, stream>>>(y_b, wpj, (float*)d_out, 1024, 1024);
}

// Round 9
// 169.972 us; speedup vs baseline: 1.1185x; 1.1185x over previous
//
#include <hip/hip_runtime.h>

// Shapes (fixed): B=2, T=2048, E=1024, H=16, Hkv=4, D=64, G=4, W=1024
// Scores bounded: q rmsnormed (|q|=8) * 0.125 * k rmsnormed (|k|=8) => |s| <= 8.
// log2(e) folded into q; softmax uses exp2 with FIXED max M = 8*log2(e).
// Attention R9: head-shared staging at FULL wave density. R8 showed staging
// amortization works (FETCH 18.8->6.2MB) but 4-wave blocks = 1 wave/SIMD
// exposed all latency (73us). Now: 1024-thread block = 16 waves = 64 q-rows
// x 4 heads of one (b,hkv); wave w: rows (w&3)*16, head w>>2 - per-wave code
// identical to the proven R2 wave. 256 blocks = 1/CU = 4 waves/SIMD (R2
// density) with 34 stagings/CU (vs R2's 102). Staging spread over all 1024
// threads (8B each), 1-tile-ahead register prefetch, ONE barrier per tile.
// XCD-chunked bid: each XCD owns one (b,hkv) K/V panel (512KB, L2-resident).
// R7: XCD-aware chunked remap on both GEMMs (T1).
// R6: gemm_bf16 128x128 tile, BK=128 dbuf, 64 MFMA/barrier, 1 block/CU.
// GEMM staging: XOR-swizzled LDS 16B-groups (grp ^ row&7) -> conflict-free.

typedef float f32x4 __attribute__((ext_vector_type(4)));
typedef short s16x8 __attribute__((ext_vector_type(8)));
typedef short s16x4 __attribute__((ext_vector_type(4)));
typedef _Float16 f16x4 __attribute__((ext_vector_type(4)));

__device__ __forceinline__ unsigned short f2bf(float f) {
  unsigned u = __float_as_uint(f);
  u += 0x7fffu + ((u >> 16) & 1u);   // RNE
  return (unsigned short)(u >> 16);
}
__device__ __forceinline__ unsigned short h16(float f) {
  _Float16 h = (_Float16)f;
  return __builtin_bit_cast(unsigned short, h);
}

__device__ __forceinline__ float fexp2(float x) {
#if __has_builtin(__builtin_amdgcn_exp2f)
  return __builtin_amdgcn_exp2f(x);
#else
  return __expf(x * 0.69314718f);
#endif
}

// async global->LDS, 16B per lane; LDS dest = wave-uniform base + lane*16
__device__ __forceinline__ void gl2lds16(const unsigned short* g, unsigned short* l) {
  __builtin_amdgcn_global_load_lds((const __attribute__((address_space(1))) unsigned int*)g,
                                   (__attribute__((address_space(3))) unsigned int*)l, 16, 0, 0);
}

// ---------------- fp32->bf16 converts + gate, one launch ----------------
__global__ __launch_bounds__(256) void cvt_gate(
    const float* __restrict__ x, const float* __restrict__ wq, const float* __restrict__ wk,
    const float* __restrict__ wv, const float* __restrict__ wp, const float* __restrict__ wgate,
    unsigned short* __restrict__ xb, unsigned short* __restrict__ wqkv,
    unsigned short* __restrict__ wpj, float* __restrict__ gatep) {
  int blk = blockIdx.x;
  if (blk < 6656) {
    int i = blk * 256 + threadIdx.x;  // float4 index, total 1703936
    const float* s;
    unsigned short* d;
    if (i < 1048576) { s = x; d = xb; }
    else if (i < 1310720) { i -= 1048576; s = wq; d = wqkv; }
    else if (i < 1376256) { i -= 1310720; s = wk; d = wqkv + 1048576; }
    else if (i < 1441792) { i -= 1376256; s = wv; d = wqkv + 1310720; }
    else { i -= 1441792; s = wp; d = wpj; }
    float4 v = ((const float4*)s)[i];
    ushort4 o;
    o.x = f2bf(v.x); o.y = f2bf(v.y); o.z = f2bf(v.z); o.w = f2bf(v.w);
    ((ushort4*)d)[i] = o;
  } else {
    int i = (blk - 6656) * 256 + threadIdx.x;  // i = bt*4 + h, total 16384
    int bt = i >> 2, h = i & 3;
    const float4* xp = (const float4*)(x + (size_t)bt * 1024);
    const float4* wpt = (const float4*)(wgate + h * 32);
    float s = 0.f;
#pragma unroll
    for (int j = 0; j < 8; ++j) {
      float4 a = xp[j], b = wpt[j];
      s += a.x * b.x + a.y * b.y + a.z * b.z + a.w * b.w;
    }
    gatep[i] = 2.f / (1.f + __expf(-s));
  }
}

// ---- fused QKV GEMM (64x128 tile, BK=128, swizzled LDS) + RoPE/RMSNorm/gate-ve ----
// A = xb (4096x1024), B = wqkv (1536x1024). Col-tile bn: 0-7 q, 8-9 k, 10-11 v.
// v-epilogue writes vp2 tiled layout directly (transpose_v fused).
__global__ __launch_bounds__(256) void gemm_qkv(
    const unsigned short* __restrict__ A, const unsigned short* __restrict__ B,
    const float* __restrict__ cosp, const float* __restrict__ sinp,
    const float* __restrict__ gatep, const float* __restrict__ ve,
    unsigned short* __restrict__ q_r, unsigned short* __restrict__ k_r,
    unsigned short* __restrict__ vp2) {
  __shared__ unsigned short smem[24576];   // As 64x128 | Bs 128x128; epilogue aliases
  unsigned short* As = smem;               // 8192 elems
  unsigned short* Bs = smem + 8192;        // 16384 elems
  const int K = 1024;
  // R7 XCD chunked remap: 768 blocks, 96/XCD; XCD x gets bm in [8x, 8x+8)
  int lin = blockIdx.y * 12 + blockIdx.x;
  int nl = (lin & 7) * 96 + (lin >> 3);
  int bn = nl % 12, bm = nl / 12;
  int t = threadIdx.x;
  int w = t >> 6, lane = t & 63;
  int c = lane & 15, g = lane >> 4;
  int wm = w >> 1, wn = w & 1;

  f32x4 acc[2][4];
#pragma unroll
  for (int i = 0; i < 2; ++i)
#pragma unroll
    for (int j = 0; j < 4; ++j) acc[i][j] = (f32x4){0.f, 0.f, 0.f, 0.f};

  const unsigned short* Ab = A + (size_t)(bm * 64) * K;
  const unsigned short* Bb = B + (size_t)(bn * 128) * K;
  int srow = lane >> 4;                         // 0..3 (4 rows of 256B per call)
  int sgrp = lane & 15;                         // 16B group within 128-elem row

  for (int k0 = 0; k0 < K; k0 += 128) {
#pragma unroll
    for (int j = 0; j < 4; ++j) {  // A rows w*16 .. +15
      int r0 = w * 16 + j * 4;
      int r = r0 + srow;
      gl2lds16(Ab + (size_t)r * K + k0 + (sgrp ^ (r & 7)) * 8, As + r0 * 128);
    }
#pragma unroll
    for (int j = 0; j < 8; ++j) {  // B rows w*32 .. +31
      int r0 = w * 32 + j * 4;
      int r = r0 + srow;
      gl2lds16(Bb + (size_t)r * K + k0 + (sgrp ^ (r & 7)) * 8, Bs + r0 * 128);
    }
    __syncthreads();
#pragma unroll
    for (int kk = 0; kk < 4; ++kk) {
      int sw = ((kk * 4 + g) ^ (c & 7)) * 8;  // row&7 == c&7 for all tiles
      s16x8 af[2], bf[4];
#pragma unroll
      for (int mt = 0; mt < 2; ++mt)
        af[mt] = *(const s16x8*)(As + (wm * 32 + mt * 16 + c) * 128 + sw);
#pragma unroll
      for (int nt = 0; nt < 4; ++nt)
        bf[nt] = *(const s16x8*)(Bs + (wn * 64 + nt * 16 + c) * 128 + sw);
#pragma unroll
      for (int mt = 0; mt < 2; ++mt)
#pragma unroll
        for (int nt = 0; nt < 4; ++nt)
          acc[mt][nt] = __builtin_amdgcn_mfma_f32_16x16x32_bf16(af[mt], bf[nt], acc[mt][nt], 0, 0, 0);
    }
    __syncthreads();
  }

  // epilogue: lane (c,g) reg r of (mt,nt): local row = wm*32+mt*16+g*4+r,
  // within-head d = nt*16 + c (head = 64 cols = wn half-tile)
  const float QSCL = 0.125f * 1.44269504f;
  if (bn < 10) {  // q/k: rope + rmsnorm -> wave-private LDS transpose -> b128 stores
    unsigned short* eb = smem + w * 2176;  // 32 x 68
#pragma unroll
    for (int mt = 0; mt < 2; ++mt) {
#pragma unroll
      for (int r = 0; r < 4; ++r) {
        int lrow = mt * 16 + g * 4 + r;
        int rowg = bm * 64 + wm * 32 + lrow;
        int tt = rowg & 2047;
        float v0 = acc[mt][0][r], v1 = acc[mt][1][r], v2 = acc[mt][2][r], v3 = acc[mt][3][r];
        float cs0 = cosp[tt * 32 + c], sn0 = sinp[tt * 32 + c];
        float cs1 = cosp[tt * 32 + 16 + c], sn1 = sinp[tt * 32 + 16 + c];
        float r0 = v0 * cs0 + v2 * sn0;
        float r1 = v1 * cs1 + v3 * sn1;
        float r2 = v2 * cs0 - v0 * sn0;
        float r3 = v3 * cs1 - v1 * sn1;
        float ss = r0 * r0 + r1 * r1 + r2 * r2 + r3 * r3;
        ss += __shfl_xor(ss, 1);
        ss += __shfl_xor(ss, 2);
        ss += __shfl_xor(ss, 4);
        ss += __shfl_xor(ss, 8);
        float sc = rsqrtf(ss * (1.0f / 64.0f) + 1.1920929e-07f);
        if (bn < 8) sc *= QSCL;
        eb[lrow * 68 + c] = f2bf(r0 * sc);
        eb[lrow * 68 + 16 + c] = f2bf(r1 * sc);
        eb[lrow * 68 + 32 + c] = f2bf(r2 * sc);
        eb[lrow * 68 + 48 + c] = f2bf(r3 * sc);
      }
    }
    asm volatile("s_waitcnt lgkmcnt(0)" ::: "memory");  // wave-private
#pragma unroll
    for (int j = 0; j < 4; ++j) {
      int idx = lane * 4 + j;  // 256 chunks: 32 rows x 8
      int lrow = idx >> 3;
      int ck = idx & 7;
      s16x8 val = *(const s16x8*)(eb + lrow * 68 + ck * 8);
      int rowg = bm * 64 + wm * 32 + lrow;
      int b = rowg >> 11, tt = rowg & 2047;
      unsigned short* dst;
      if (bn < 8) dst = q_r + ((size_t)(b * 16 + bn * 2 + wn) * 2048 + tt) * 64 + ck * 8;
      else dst = k_r + ((size_t)(b * 4 + (bn - 8) * 2 + wn) * 2048 + tt) * 64 + ck * 8;
      *(s16x8*)dst = val;
    }
  } else {  // v: + gate*ve, transpose to vp2 tiled [s][tile32][d][32keys] fp16
    unsigned short* eb = smem + w * 2560;  // 64 d x 40 (keys padded)
    int h = (bn - 10) * 2 + wn;
#pragma unroll
    for (int mt = 0; mt < 2; ++mt) {
#pragma unroll
      for (int r = 0; r < 4; ++r) {
        int key = mt * 16 + g * 4 + r;               // 0..31 within wave tile
        int rowg = bm * 64 + wm * 32 + key;
        float gate = gatep[rowg * 4 + h];
        const float* vep = ve + (size_t)rowg * 256 + h * 64;
        eb[(0 * 16 + c) * 40 + key] = h16(acc[mt][0][r] + gate * vep[c]);
        eb[(1 * 16 + c) * 40 + key] = h16(acc[mt][1][r] + gate * vep[16 + c]);
        eb[(2 * 16 + c) * 40 + key] = h16(acc[mt][2][r] + gate * vep[32 + c]);
        eb[(3 * 16 + c) * 40 + key] = h16(acc[mt][3][r] + gate * vep[48 + c]);
      }
    }
    asm volatile("s_waitcnt lgkmcnt(0)" ::: "memory");  // wave-private
    int rowg0 = bm * 64 + wm * 32;
    int b = rowg0 >> 11;
    int tile = (rowg0 & 2047) >> 5;
    unsigned short* vb = vp2 + ((size_t)(b * 4 + h) * 64 + tile) * 2048;
#pragma unroll
    for (int j = 0; j < 4; ++j) {
      int cid = j * 64 + lane;  // 256 chunks: 64 d x 4 keygroups
      int d = cid >> 2;
      int kg = cid & 3;
      s16x8 val = *(const s16x8*)(eb + d * 40 + kg * 8);
      *(s16x8*)(vb + d * 32 + kg * 8) = val;
    }
  }
}

// ------- bf16 GEMM 128x128 (m97 structure), BK=128 dbuf, C = A @ B^T -------
// 4 waves, each 64x64 output: 16 MFMA per 8 ds_reads per kk, 64 MFMA/barrier.
// Grid (N/128, M/128) = (8,32) = 256 blocks = exactly 1 block/CU.
__global__ __launch_bounds__(256) void gemm_bf16_128(
    const unsigned short* __restrict__ A, const unsigned short* __restrict__ B,
    float* __restrict__ C, int K, int ldc) {
  __shared__ unsigned short As[2][128 * 128];
  __shared__ unsigned short Bs[2][128 * 128];
  // R7 XCD chunked remap: 256 blocks, 32/XCD; XCD x gets bm in [4x, 4x+4)
  int lin = blockIdx.y * 8 + blockIdx.x;
  int nl = (lin & 7) * 32 + (lin >> 3);
  int bn = nl & 7, bm = nl >> 3;
  int t = threadIdx.x;
  int w = t >> 6, lane = t & 63;
  int c = lane & 15, g = lane >> 4;
  int wm = w >> 1, wn = w & 1;

  f32x4 acc[4][4];
#pragma unroll
  for (int i = 0; i < 4; ++i)
#pragma unroll
    for (int j = 0; j < 4; ++j) acc[i][j] = (f32x4){0.f, 0.f, 0.f, 0.f};

  const unsigned short* Ab = A + (size_t)(bm * 128) * K;
  const unsigned short* Bb = B + (size_t)(bn * 128) * K;
  int srow = lane >> 4;   // 0..3
  int sgrp = lane & 15;   // 16B group within 128-elem row

  // stage K-step k0 into buffer buf: each wave stages its 32 rows of A and B
#define STAGE128(buf, k0)                                                          \
  {                                                                                \
    _Pragma("unroll")                                                              \
    for (int j = 0; j < 8; ++j) {                                                  \
      int r0 = w * 32 + j * 4;                                                     \
      int r = r0 + srow;                                                           \
      gl2lds16(Ab + (size_t)r * K + (k0) + (sgrp ^ (r & 7)) * 8, &As[buf][r0 * 128]); \
      gl2lds16(Bb + (size_t)r * K + (k0) + (sgrp ^ (r & 7)) * 8, &Bs[buf][r0 * 128]); \
    }                                                                              \
  }

  STAGE128(0, 0);
  for (int tstep = 0; tstep < 8; ++tstep) {
    int buf = tstep & 1;
    __syncthreads();  // drains this wave's vmcnt -> buf staged; all waves synced
    if (tstep < 7) STAGE128(buf ^ 1, (tstep + 1) * 128);
#pragma unroll
    for (int kk = 0; kk < 4; ++kk) {
      int sw = ((kk * 4 + g) ^ (c & 7)) * 8;
      s16x8 af[4], bf[4];
#pragma unroll
      for (int mt = 0; mt < 4; ++mt)
        af[mt] = *(const s16x8*)(&As[buf][(wm * 64 + mt * 16 + c) * 128 + sw]);
#pragma unroll
      for (int nt = 0; nt < 4; ++nt)
        bf[nt] = *(const s16x8*)(&Bs[buf][(wn * 64 + nt * 16 + c) * 128 + sw]);
#pragma unroll
      for (int mt = 0; mt < 4; ++mt)
#pragma unroll
        for (int nt = 0; nt < 4; ++nt)
          acc[mt][nt] = __builtin_amdgcn_mfma_f32_16x16x32_bf16(af[mt], bf[nt], acc[mt][nt], 0, 0, 0);
    }
  }
#undef STAGE128

#pragma unroll
  for (int mt = 0; mt < 4; ++mt)
#pragma unroll
    for (int nt = 0; nt < 4; ++nt)
#pragma unroll
      for (int r = 0; r < 4; ++r) {
        int rowg = bm * 128 + wm * 64 + mt * 16 + g * 4 + r;
        int colg = bn * 128 + wn * 64 + nt * 16 + c;
        C[(size_t)rowg * ldc + colg] = acc[mt][nt][r];
      }
}

// ---- flash attention R9: head-shared staging, 16 waves (4/SIMD) ----
// Block = 1024 threads: 64 q-rows x 4 heads of one (b,hkv). Wave w:
// rows (w&3)*16, head w>>2. Stage K/V tile once (8B/thread); ONE barrier
// per 32-key tile; per-wave compute identical to the proven R2 wave.
__global__ __launch_bounds__(1024) void attn_kernel(
    const unsigned short* __restrict__ q_r, const unsigned short* __restrict__ k_r,
    const unsigned short* __restrict__ v_p2, unsigned short* __restrict__ y_b,
    const int* __restrict__ wptr) {
  const int W = *wptr;
  const int bid0 = blockIdx.x;
  // XCD-chunked: XCD x (= bid0 & 7) owns panel (b*4+hkv) = x -> K/V L2-resident
  const int bid = (bid0 & 7) * 32 + (bid0 >> 3);
  const int qt = bid & 31;
  const int hkv = (bid >> 5) & 3;
  const int b = bid >> 7;
  const int tid = threadIdx.x;
  const int w = tid >> 6, lane = tid & 63, c = lane & 15, g = lane >> 4;
  const int wq = w & 3, wh = w >> 2;
  const int r0b = qt * 64;
  const int r0w = r0b + wq * 16;
  const int h = hkv * 4 + wh;
  const float M = 11.5415603f;  // 8 * log2(e)

  __shared__ unsigned short Ks[2][32 * 68];
  __shared__ unsigned short Vs[2][64 * 40];

  const unsigned short* kbase = k_r + (size_t)(b * 4 + hkv) * 131072;
  const unsigned short* vbase = v_p2 + (size_t)(b * 4 + hkv) * 131072;
  const unsigned short* qbase = q_r + ((size_t)(b * 16 + h) * 2048 + r0w) * 64;

  s16x8 q_lo = *(const s16x8*)(qbase + c * 64 + g * 8);
  s16x8 q_hi = *(const s16x8*)(qbase + c * 64 + 32 + g * 8);

  int kt0w = r0w - W; if (kt0w < 0) kt0w = 0;
  const int ktEw = r0w + 16;
  int KT0 = r0b - W; if (KT0 < 0) KT0 = 0;
  KT0 &= ~31;
  const int KTE = r0b + 64;

  float l_part = 0.f;
  f32x4 acc[4];
#pragma unroll
  for (int dt = 0; dt < 4; ++dt) acc[dt] = (f32x4){0.f, 0.f, 0.f, 0.f};

  // staging split: tid<512 stage K (4 elems each), tid>=512 stage V.
  const bool isK = tid < 512;
  const int kkey = tid >> 4, kcg = (tid & 15) * 4;          // K: key, 4-elem col group
  const int vj = tid - 512;                                  // V: 4-elem chunk id
  const int ldsOff = isK ? (kkey * 68 + kcg) : ((vj >> 3) * 40 + (vj & 7) * 4);

  s16x4 pfr;
  {
    const unsigned short* src = isK
        ? (kbase + (size_t)(KT0 + kkey) * 64 + kcg)
        : (vbase + (size_t)(KT0 >> 5) * 2048 + vj * 4);
    pfr = *(const s16x4*)src;
  }

  const int qrow = r0w + c;

  int bufI = 0;
  for (int kt = KT0; kt < KTE; kt += 32, bufI ^= 1) {
    int nkt = (kt + 32 < KTE) ? kt + 32 : kt;
    const unsigned short* nsrc = isK
        ? (kbase + (size_t)(nkt + kkey) * 64 + kcg)
        : (vbase + (size_t)(nkt >> 5) * 2048 + vj * 4);
    s16x4 nfr = *(const s16x4*)nsrc;

    // stage into buf bufI (other buffer may still be read by lagging waves - safe)
    unsigned short* dst = isK ? &Ks[bufI][ldsOff] : &Vs[bufI][ldsOff];
    *(s16x4*)dst = pfr;
    __syncthreads();  // the ONLY barrier per tile

    if (kt + 32 > kt0w && kt < ktEw) {
      const unsigned short* kr0 = &Ks[bufI][c * 68 + g * 8];
      s16x4 a0 = *(const s16x4*)(kr0);
      s16x4 a1 = *(const s16x4*)(kr0 + 4);
      s16x4 a2 = *(const s16x4*)(kr0 + 32);
      s16x4 a3 = *(const s16x4*)(kr0 + 36);
      const unsigned short* kr1 = kr0 + 16 * 68;
      s16x4 a4 = *(const s16x4*)(kr1);
      s16x4 a5 = *(const s16x4*)(kr1 + 4);
      s16x4 a6 = *(const s16x4*)(kr1 + 32);
      s16x4 a7 = *(const s16x4*)(kr1 + 36);
      s16x8 k0lo = __builtin_shufflevector(a0, a1, 0, 1, 2, 3, 4, 5, 6, 7);
      s16x8 k0hi = __builtin_shufflevector(a2, a3, 0, 1, 2, 3, 4, 5, 6, 7);
      s16x8 k1lo = __builtin_shufflevector(a4, a5, 0, 1, 2, 3, 4, 5, 6, 7);
      s16x8 k1hi = __builtin_shufflevector(a6, a7, 0, 1, 2, 3, 4, 5, 6, 7);

      f32x4 S0 = (f32x4){0.f, 0.f, 0.f, 0.f};
      f32x4 S1 = (f32x4){0.f, 0.f, 0.f, 0.f};
      S0 = __builtin_amdgcn_mfma_f32_16x16x32_bf16(k0lo, q_lo, S0, 0, 0, 0);
      S0 = __builtin_amdgcn_mfma_f32_16x16x32_bf16(k0hi, q_hi, S0, 0, 0, 0);
      S1 = __builtin_amdgcn_mfma_f32_16x16x32_bf16(k1lo, q_lo, S1, 0, 0, 0);
      S1 = __builtin_amdgcn_mfma_f32_16x16x32_bf16(k1hi, q_hi, S1, 0, 0, 0);

      f16x4 P0, P1;
      const bool edge = (kt < kt0w + 32) || (kt + 32 > r0w);
#pragma unroll
      for (int r = 0; r < 4; ++r) {
        float p0 = fexp2(S0[r] - M);
        float p1 = fexp2(S1[r] - M);
        if (edge) {
          int k0i = kt + g * 4 + r;
          int k1i = k0i + 16;
          if (!(k0i <= qrow && k0i >= qrow - W)) p0 = 0.f;
          if (!(k1i <= qrow && k1i >= qrow - W)) p1 = 0.f;
        }
        l_part += p0 + p1;
        P0[r] = (_Float16)p0;
        P1[r] = (_Float16)p1;
      }

#pragma unroll
      for (int dt = 0; dt < 4; ++dt) {
        const unsigned short* vr = &Vs[bufI][(dt * 16 + c) * 40 + g * 4];
        f16x4 va = *(const f16x4*)(vr);
        f16x4 vb = *(const f16x4*)(vr + 16);
        acc[dt] = __builtin_amdgcn_mfma_f32_16x16x16f16(va, P0, acc[dt], 0, 0, 0);
        acc[dt] = __builtin_amdgcn_mfma_f32_16x16x16f16(vb, P1, acc[dt], 0, 0, 0);
      }
    }
    pfr = nfr;
  }

  float l = l_part;
  l += __shfl_xor(l, 16);
  l += __shfl_xor(l, 32);
  float inv = 1.0f / l;

  unsigned short* ob = y_b + ((size_t)(b * 2048 + r0w + c) * 16 + h) * 64 + g * 4;
#pragma unroll
  for (int dt = 0; dt < 4; ++dt) {
    ushort4 o;
    o.x = f2bf(acc[dt][0] * inv);
    o.y = f2bf(acc[dt][1] * inv);
    o.z = f2bf(acc[dt][2] * inv);
    o.w = f2bf(acc[dt][3] * inv);
    *(ushort4*)(ob + dt * 16) = o;
  }
}

extern "C" void kernel_launch(void* const* d_in, const int* in_sizes, int n_in,
                              void* d_out, int out_size, void* d_ws, size_t ws_size,
                              hipStream_t stream) {
  const float* x = (const float*)d_in[0];
  const float* ve = (const float*)d_in[1];
  const float* cosp = (const float*)d_in[2];
  const float* sinp = (const float*)d_in[3];
  const float* Wq = (const float*)d_in[4];
  const float* Wk = (const float*)d_in[5];
  const float* Wv = (const float*)d_in[6];
  const float* Wproj = (const float*)d_in[7];
  const float* Wgate = (const float*)d_in[8];
  const int* wptr = (const int*)d_in[9];

  unsigned short* xb = (unsigned short*)d_ws;        // 4096x1024 bf16
  unsigned short* wqkv = xb + 4194304;               // 1536x1024 bf16
  unsigned short* wpj = wqkv + 1572864;              // 1024x1024 bf16
  unsigned short* q_r = wpj + 1048576;               // [B,H,T,D] bf16
  unsigned short* k_r = q_r + 4194304;               // [B,Hkv,T,D] bf16
  unsigned short* y_b = k_r + 1048576;               // [B,T,H,D] bf16
  unsigned short* vp2 = y_b + 4194304;               // [B*Hkv][T/32][64][32] fp16
  float* gatep = (float*)(vp2 + 1048576);            // [4096][4] fp32

  cvt_gate<<<6720, 256, 0, stream>>>(x, Wq, Wk, Wv, Wproj, Wgate, xb, wqkv, wpj, gatep);
  gemm_qkv<<<dim3(12, 64), 256, 0, stream>>>(xb, wqkv, cosp, sinp, gatep, ve, q_r, k_r, vp2);
  attn_kernel<<<256, 1024, 0, stream>>>(q_r, k_r, vp2, y_b, wptr);
  gemm_bf16_128<<<dim3(8, 32), 256, 0, stream>>>(y_b, wpj, (float*)d_out, 1024, 1024);
}

// Round 10
// 168.636 us; speedup vs baseline: 1.1273x; 1.0079x over previous
//
#include <hip/hip_runtime.h>

// Shapes (fixed): B=2, T=2048, E=1024, H=16, Hkv=4, D=64, G=4, W=1024
// Scores bounded: q rmsnormed (|q|=8) * 0.125 * k rmsnormed (|k|=8) => |s| <= 8.
// log2(e) folded into q; softmax uses exp2 with FIXED max M = 8*log2(e).
// Attention: R2 structure (best measured: R7=165.8us): S^T = K·Q^T, 32-key
// tiles, dbuf LDS, ONE barrier/tile, register prefetch, R1 balanced qt remap.
// R10: K-tile LDS layout 68-pad -> XOR-swizzled [32][64] (16B grp ^ row&7),
// the same swizzle the GEMMs use. Kills the ~4-way bank conflict of the
// 136B-stride reads (4.08M conflicts/dispatch) AND replaces 2x ds_write_b64
// + 8x ds_read_b64 + 8x shufflevector repacks with 1x b128 write + 4x b128
// reads per tile. V layout (40-pad, 2-way=free) untouched.
// R5 (64-key tiles), R8 (4-wave head-share), R9 (16-wave head-share) all
// regressed or neutral vs this structure -> structural attn search closed.
// R7: XCD-aware chunked remap on both GEMMs (T1).
// R6: gemm_bf16 128x128 tile, BK=128 dbuf, 64 MFMA/barrier, 1 block/CU.
// GEMM staging: XOR-swizzled LDS 16B-groups (grp ^ row&7) -> conflict-free
// reads while keeping global_load_lds's wave-uniform-base staging.

typedef float f32x4 __attribute__((ext_vector_type(4)));
typedef short s16x8 __attribute__((ext_vector_type(8)));
typedef short s16x4 __attribute__((ext_vector_type(4)));
typedef _Float16 f16x4 __attribute__((ext_vector_type(4)));

__device__ __forceinline__ unsigned short f2bf(float f) {
  unsigned u = __float_as_uint(f);
  u += 0x7fffu + ((u >> 16) & 1u);   // RNE
  return (unsigned short)(u >> 16);
}
__device__ __forceinline__ unsigned short h16(float f) {
  _Float16 h = (_Float16)f;
  return __builtin_bit_cast(unsigned short, h);
}

__device__ __forceinline__ float fexp2(float x) {
#if __has_builtin(__builtin_amdgcn_exp2f)
  return __builtin_amdgcn_exp2f(x);
#else
  return __expf(x * 0.69314718f);
#endif
}

// async global->LDS, 16B per lane; LDS dest = wave-uniform base + lane*16
__device__ __forceinline__ void gl2lds16(const unsigned short* g, unsigned short* l) {
  __builtin_amdgcn_global_load_lds((const __attribute__((address_space(1))) unsigned int*)g,
                                   (__attribute__((address_space(3))) unsigned int*)l, 16, 0, 0);
}

// ---------------- fp32->bf16 converts + gate, one launch ----------------
__global__ __launch_bounds__(256) void cvt_gate(
    const float* __restrict__ x, const float* __restrict__ wq, const float* __restrict__ wk,
    const float* __restrict__ wv, const float* __restrict__ wp, const float* __restrict__ wgate,
    unsigned short* __restrict__ xb, unsigned short* __restrict__ wqkv,
    unsigned short* __restrict__ wpj, float* __restrict__ gatep) {
  int blk = blockIdx.x;
  if (blk < 6656) {
    int i = blk * 256 + threadIdx.x;  // float4 index, total 1703936
    const float* s;
    unsigned short* d;
    if (i < 1048576) { s = x; d = xb; }
    else if (i < 1310720) { i -= 1048576; s = wq; d = wqkv; }
    else if (i < 1376256) { i -= 1310720; s = wk; d = wqkv + 1048576; }
    else if (i < 1441792) { i -= 1376256; s = wv; d = wqkv + 1310720; }
    else { i -= 1441792; s = wp; d = wpj; }
    float4 v = ((const float4*)s)[i];
    ushort4 o;
    o.x = f2bf(v.x); o.y = f2bf(v.y); o.z = f2bf(v.z); o.w = f2bf(v.w);
    ((ushort4*)d)[i] = o;
  } else {
    int i = (blk - 6656) * 256 + threadIdx.x;  // i = bt*4 + h, total 16384
    int bt = i >> 2, h = i & 3;
    const float4* xp = (const float4*)(x + (size_t)bt * 1024);
    const float4* wpt = (const float4*)(wgate + h * 32);
    float s = 0.f;
#pragma unroll
    for (int j = 0; j < 8; ++j) {
      float4 a = xp[j], b = wpt[j];
      s += a.x * b.x + a.y * b.y + a.z * b.z + a.w * b.w;
    }
    gatep[i] = 2.f / (1.f + __expf(-s));
  }
}

// ---- fused QKV GEMM (64x128 tile, BK=128, swizzled LDS) + RoPE/RMSNorm/gate-ve ----
// A = xb (4096x1024), B = wqkv (1536x1024). Col-tile bn: 0-7 q, 8-9 k, 10-11 v.
// v-epilogue writes vp2 tiled layout directly (transpose_v fused).
__global__ __launch_bounds__(256) void gemm_qkv(
    const unsigned short* __restrict__ A, const unsigned short* __restrict__ B,
    const float* __restrict__ cosp, const float* __restrict__ sinp,
    const float* __restrict__ gatep, const float* __restrict__ ve,
    unsigned short* __restrict__ q_r, unsigned short* __restrict__ k_r,
    unsigned short* __restrict__ vp2) {
  __shared__ unsigned short smem[24576];   // As 64x128 | Bs 128x128; epilogue aliases
  unsigned short* As = smem;               // 8192 elems
  unsigned short* Bs = smem + 8192;        // 16384 elems
  const int K = 1024;
  // R7 XCD chunked remap: 768 blocks, 96/XCD; XCD x gets bm in [8x, 8x+8)
  int lin = blockIdx.y * 12 + blockIdx.x;
  int nl = (lin & 7) * 96 + (lin >> 3);
  int bn = nl % 12, bm = nl / 12;
  int t = threadIdx.x;
  int w = t >> 6, lane = t & 63;
  int c = lane & 15, g = lane >> 4;
  int wm = w >> 1, wn = w & 1;

  f32x4 acc[2][4];
#pragma unroll
  for (int i = 0; i < 2; ++i)
#pragma unroll
    for (int j = 0; j < 4; ++j) acc[i][j] = (f32x4){0.f, 0.f, 0.f, 0.f};

  const unsigned short* Ab = A + (size_t)(bm * 64) * K;
  const unsigned short* Bb = B + (size_t)(bn * 128) * K;
  int srow = lane >> 4;                         // 0..3 (4 rows of 256B per call)
  int sgrp = lane & 15;                         // 16B group within 128-elem row

  for (int k0 = 0; k0 < K; k0 += 128) {
#pragma unroll
    for (int j = 0; j < 4; ++j) {  // A rows w*16 .. +15
      int r0 = w * 16 + j * 4;
      int r = r0 + srow;
      gl2lds16(Ab + (size_t)r * K + k0 + (sgrp ^ (r & 7)) * 8, As + r0 * 128);
    }
#pragma unroll
    for (int j = 0; j < 8; ++j) {  // B rows w*32 .. +31
      int r0 = w * 32 + j * 4;
      int r = r0 + srow;
      gl2lds16(Bb + (size_t)r * K + k0 + (sgrp ^ (r & 7)) * 8, Bs + r0 * 128);
    }
    __syncthreads();
#pragma unroll
    for (int kk = 0; kk < 4; ++kk) {
      int sw = ((kk * 4 + g) ^ (c & 7)) * 8;  // row&7 == c&7 for all tiles
      s16x8 af[2], bf[4];
#pragma unroll
      for (int mt = 0; mt < 2; ++mt)
        af[mt] = *(const s16x8*)(As + (wm * 32 + mt * 16 + c) * 128 + sw);
#pragma unroll
      for (int nt = 0; nt < 4; ++nt)
        bf[nt] = *(const s16x8*)(Bs + (wn * 64 + nt * 16 + c) * 128 + sw);
#pragma unroll
      for (int mt = 0; mt < 2; ++mt)
#pragma unroll
        for (int nt = 0; nt < 4; ++nt)
          acc[mt][nt] = __builtin_amdgcn_mfma_f32_16x16x32_bf16(af[mt], bf[nt], acc[mt][nt], 0, 0, 0);
    }
    __syncthreads();
  }

  // epilogue: lane (c,g) reg r of (mt,nt): local row = wm*32+mt*16+g*4+r,
  // within-head d = nt*16 + c (head = 64 cols = wn half-tile)
  const float QSCL = 0.125f * 1.44269504f;
  if (bn < 10) {  // q/k: rope + rmsnorm -> wave-private LDS transpose -> b128 stores
    unsigned short* eb = smem + w * 2176;  // 32 x 68
#pragma unroll
    for (int mt = 0; mt < 2; ++mt) {
#pragma unroll
      for (int r = 0; r < 4; ++r) {
        int lrow = mt * 16 + g * 4 + r;
        int rowg = bm * 64 + wm * 32 + lrow;
        int tt = rowg & 2047;
        float v0 = acc[mt][0][r], v1 = acc[mt][1][r], v2 = acc[mt][2][r], v3 = acc[mt][3][r];
        float cs0 = cosp[tt * 32 + c], sn0 = sinp[tt * 32 + c];
        float cs1 = cosp[tt * 32 + 16 + c], sn1 = sinp[tt * 32 + 16 + c];
        float r0 = v0 * cs0 + v2 * sn0;
        float r1 = v1 * cs1 + v3 * sn1;
        float r2 = v2 * cs0 - v0 * sn0;
        float r3 = v3 * cs1 - v1 * sn1;
        float ss = r0 * r0 + r1 * r1 + r2 * r2 + r3 * r3;
        ss += __shfl_xor(ss, 1);
        ss += __shfl_xor(ss, 2);
        ss += __shfl_xor(ss, 4);
        ss += __shfl_xor(ss, 8);
        float sc = rsqrtf(ss * (1.0f / 64.0f) + 1.1920929e-07f);
        if (bn < 8) sc *= QSCL;
        eb[lrow * 68 + c] = f2bf(r0 * sc);
        eb[lrow * 68 + 16 + c] = f2bf(r1 * sc);
        eb[lrow * 68 + 32 + c] = f2bf(r2 * sc);
        eb[lrow * 68 + 48 + c] = f2bf(r3 * sc);
      }
    }
    asm volatile("s_waitcnt lgkmcnt(0)" ::: "memory");  // wave-private
#pragma unroll
    for (int j = 0; j < 4; ++j) {
      int idx = lane * 4 + j;  // 256 chunks: 32 rows x 8
      int lrow = idx >> 3;
      int ck = idx & 7;
      s16x8 val = *(const s16x8*)(eb + lrow * 68 + ck * 8);
      int rowg = bm * 64 + wm * 32 + lrow;
      int b = rowg >> 11, tt = rowg & 2047;
      unsigned short* dst;
      if (bn < 8) dst = q_r + ((size_t)(b * 16 + bn * 2 + wn) * 2048 + tt) * 64 + ck * 8;
      else dst = k_r + ((size_t)(b * 4 + (bn - 8) * 2 + wn) * 2048 + tt) * 64 + ck * 8;
      *(s16x8*)dst = val;
    }
  } else {  // v: + gate*ve, transpose to vp2 tiled [s][tile32][d][32keys] fp16
    unsigned short* eb = smem + w * 2560;  // 64 d x 40 (keys padded)
    int h = (bn - 10) * 2 + wn;
#pragma unroll
    for (int mt = 0; mt < 2; ++mt) {
#pragma unroll
      for (int r = 0; r < 4; ++r) {
        int key = mt * 16 + g * 4 + r;               // 0..31 within wave tile
        int rowg = bm * 64 + wm * 32 + key;
        float gate = gatep[rowg * 4 + h];
        const float* vep = ve + (size_t)rowg * 256 + h * 64;
        eb[(0 * 16 + c) * 40 + key] = h16(acc[mt][0][r] + gate * vep[c]);
        eb[(1 * 16 + c) * 40 + key] = h16(acc[mt][1][r] + gate * vep[16 + c]);
        eb[(2 * 16 + c) * 40 + key] = h16(acc[mt][2][r] + gate * vep[32 + c]);
        eb[(3 * 16 + c) * 40 + key] = h16(acc[mt][3][r] + gate * vep[48 + c]);
      }
    }
    asm volatile("s_waitcnt lgkmcnt(0)" ::: "memory");  // wave-private
    int rowg0 = bm * 64 + wm * 32;
    int b = rowg0 >> 11;
    int tile = (rowg0 & 2047) >> 5;
    unsigned short* vb = vp2 + ((size_t)(b * 4 + h) * 64 + tile) * 2048;
#pragma unroll
    for (int j = 0; j < 4; ++j) {
      int cid = j * 64 + lane;  // 256 chunks: 64 d x 4 keygroups
      int d = cid >> 2;
      int kg = cid & 3;
      s16x8 val = *(const s16x8*)(eb + d * 40 + kg * 8);
      *(s16x8*)(vb + d * 32 + kg * 8) = val;
    }
  }
}

// ------- bf16 GEMM 128x128 (m97 structure), BK=128 dbuf, C = A @ B^T -------
// 4 waves, each 64x64 output: 16 MFMA per 8 ds_reads per kk, 64 MFMA/barrier.
// Grid (N/128, M/128) = (8,32) = 256 blocks = exactly 1 block/CU.
__global__ __launch_bounds__(256) void gemm_bf16_128(
    const unsigned short* __restrict__ A, const unsigned short* __restrict__ B,
    float* __restrict__ C, int K, int ldc) {
  __shared__ unsigned short As[2][128 * 128];
  __shared__ unsigned short Bs[2][128 * 128];
  // R7 XCD chunked remap: 256 blocks, 32/XCD; XCD x gets bm in [4x, 4x+4)
  int lin = blockIdx.y * 8 + blockIdx.x;
  int nl = (lin & 7) * 32 + (lin >> 3);
  int bn = nl & 7, bm = nl >> 3;
  int t = threadIdx.x;
  int w = t >> 6, lane = t & 63;
  int c = lane & 15, g = lane >> 4;
  int wm = w >> 1, wn = w & 1;

  f32x4 acc[4][4];
#pragma unroll
  for (int i = 0; i < 4; ++i)
#pragma unroll
    for (int j = 0; j < 4; ++j) acc[i][j] = (f32x4){0.f, 0.f, 0.f, 0.f};

  const unsigned short* Ab = A + (size_t)(bm * 128) * K;
  const unsigned short* Bb = B + (size_t)(bn * 128) * K;
  int srow = lane >> 4;   // 0..3
  int sgrp = lane & 15;   // 16B group within 128-elem row

  // stage K-step k0 into buffer buf: each wave stages its 32 rows of A and B
#define STAGE128(buf, k0)                                                          \
  {                                                                                \
    _Pragma("unroll")                                                              \
    for (int j = 0; j < 8; ++j) {                                                  \
      int r0 = w * 32 + j * 4;                                                     \
      int r = r0 + srow;                                                           \
      gl2lds16(Ab + (size_t)r * K + (k0) + (sgrp ^ (r & 7)) * 8, &As[buf][r0 * 128]); \
      gl2lds16(Bb + (size_t)r * K + (k0) + (sgrp ^ (r & 7)) * 8, &Bs[buf][r0 * 128]); \
    }                                                                              \
  }

  STAGE128(0, 0);
  for (int tstep = 0; tstep < 8; ++tstep) {
    int buf = tstep & 1;
    __syncthreads();  // drains this wave's vmcnt -> buf staged; all waves synced
    if (tstep < 7) STAGE128(buf ^ 1, (tstep + 1) * 128);
#pragma unroll
    for (int kk = 0; kk < 4; ++kk) {
      int sw = ((kk * 4 + g) ^ (c & 7)) * 8;
      s16x8 af[4], bf[4];
#pragma unroll
      for (int mt = 0; mt < 4; ++mt)
        af[mt] = *(const s16x8*)(&As[buf][(wm * 64 + mt * 16 + c) * 128 + sw]);
#pragma unroll
      for (int nt = 0; nt < 4; ++nt)
        bf[nt] = *(const s16x8*)(&Bs[buf][(wn * 64 + nt * 16 + c) * 128 + sw]);
#pragma unroll
      for (int mt = 0; mt < 4; ++mt)
#pragma unroll
        for (int nt = 0; nt < 4; ++nt)
          acc[mt][nt] = __builtin_amdgcn_mfma_f32_16x16x32_bf16(af[mt], bf[nt], acc[mt][nt], 0, 0, 0);
    }
  }
#undef STAGE128

#pragma unroll
  for (int mt = 0; mt < 4; ++mt)
#pragma unroll
    for (int nt = 0; nt < 4; ++nt)
#pragma unroll
      for (int r = 0; r < 4; ++r) {
        int rowg = bm * 128 + wm * 64 + mt * 16 + g * 4 + r;
        int colg = bn * 128 + wn * 64 + nt * 16 + c;
        C[(size_t)rowg * ldc + colg] = acc[mt][nt][r];
      }
}

// -- flash attention: S^T form, dbuf LDS, ONE barrier/tile, swizzled K (R10) --
__global__ __launch_bounds__(256) void attn_kernel(
    const unsigned short* __restrict__ q_r, const unsigned short* __restrict__ k_r,
    const unsigned short* __restrict__ v_p2, unsigned short* __restrict__ y_b,
    const int* __restrict__ wptr) {
  const int W = *wptr;
  const int bid = blockIdx.x;
  // Balanced qt remap: co-resident blocks {c, c+256, c+512, c+768} get
  // qt = {m, 15-m, 16+m, 31-m} -> per-CU key-tile count is 102 for every m.
  const int rr = bid >> 8, cc = bid & 255;
  const int mm = cc & 7;
  const int h = (cc >> 3) & 15, b = cc >> 7;
  const int qt = (rr == 0) ? mm : (rr == 1) ? 15 - mm : (rr == 2) ? 16 + mm : 31 - mm;
  const int tid = threadIdx.x;
  const int w = tid >> 6, lane = tid & 63, c = lane & 15, g = lane >> 4;
  const int r0b = qt * 64;
  const int r0w = r0b + w * 16;
  const int hkv = h >> 2;
  const float M = 11.5415603f;  // 8 * log2(e)

  __shared__ unsigned short Ks[2][32 * 64];   // XOR-swizzled: grp ^ (row&7)
  __shared__ unsigned short Vs[2][64 * 40];

  const unsigned short* kbase = k_r + (size_t)(b * 4 + hkv) * 131072;
  const unsigned short* vbase = v_p2 + (size_t)(b * 4 + hkv) * 131072;
  const unsigned short* qbase = q_r + ((size_t)(b * 16 + h) * 2048 + r0w) * 64;

  s16x8 q_lo = *(const s16x8*)(qbase + c * 64 + g * 8);
  s16x8 q_hi = *(const s16x8*)(qbase + c * 64 + 32 + g * 8);

  int kt0w = r0w - W; if (kt0w < 0) kt0w = 0;
  const int ktEw = r0w + 16;
  int KT0 = r0b - W; if (KT0 < 0) KT0 = 0;
  KT0 &= ~31;
  const int KTE = r0b + 64;

  float l_part = 0.f;
  f32x4 acc[4];
#pragma unroll
  for (int dt = 0; dt < 4; ++dt) acc[dt] = (f32x4){0.f, 0.f, 0.f, 0.f};

  s16x8 pk = *(const s16x8*)(kbase + (size_t)KT0 * 64 + tid * 8);
  s16x8 pv = *(const s16x8*)(vbase + (size_t)(KT0 >> 5) * 2048 + tid * 8);

  // staging offsets: K row tid>>3, 16B-group tid&7 -> swizzled dest (b128-aligned)
  const int krow = tid >> 3;
  const int koff = krow * 64 + (((tid & 7) ^ (krow & 7)) * 8);
  const int voff = (tid >> 2) * 40 + (tid & 3) * 8;
  // fragment read swizzle: rows c and c+16 share (c&7)
  const int s0 = ((g ^ (c & 7)) * 8);          // dims g*8..g*8+7
  const int s1 = (((4 + g) ^ (c & 7)) * 8);    // dims 32+g*8..+7

  int bufI = 0;
  for (int kt = KT0; kt < KTE; kt += 32, bufI ^= 1) {
    int nkt = (kt + 32 < KTE) ? kt + 32 : kt;
    s16x8 nk = *(const s16x8*)(kbase + (size_t)nkt * 64 + tid * 8);
    s16x8 nv = *(const s16x8*)(vbase + (size_t)(nkt >> 5) * 2048 + tid * 8);

    // stage into buf bufI (other buffer may still be read by lagging waves - safe)
    *(s16x8*)(&Ks[bufI][koff]) = pk;
    *(s16x8*)(&Vs[bufI][voff]) = pv;
    __syncthreads();  // the ONLY barrier per tile

    if (kt + 32 > kt0w && kt < ktEw) {
      const unsigned short* krA = &Ks[bufI][c * 64];
      s16x8 k0lo = *(const s16x8*)(krA + s0);
      s16x8 k0hi = *(const s16x8*)(krA + s1);
      s16x8 k1lo = *(const s16x8*)(krA + 16 * 64 + s0);
      s16x8 k1hi = *(const s16x8*)(krA + 16 * 64 + s1);

      f32x4 S0 = (f32x4){0.f, 0.f, 0.f, 0.f};
      f32x4 S1 = (f32x4){0.f, 0.f, 0.f, 0.f};
      S0 = __builtin_amdgcn_mfma_f32_16x16x32_bf16(k0lo, q_lo, S0, 0, 0, 0);
      S0 = __builtin_amdgcn_mfma_f32_16x16x32_bf16(k0hi, q_hi, S0, 0, 0, 0);
      S1 = __builtin_amdgcn_mfma_f32_16x16x32_bf16(k1lo, q_lo, S1, 0, 0, 0);
      S1 = __builtin_amdgcn_mfma_f32_16x16x32_bf16(k1hi, q_hi, S1, 0, 0, 0);

      f16x4 P0, P1;
      const bool edge = (kt < kt0w + 32) || (kt + 32 > r0w);
      const int qrow = r0w + c;
#pragma unroll
      for (int r = 0; r < 4; ++r) {
        float p0 = fexp2(S0[r] - M);
        float p1 = fexp2(S1[r] - M);
        if (edge) {
          int k0i = kt + g * 4 + r;
          int k1i = k0i + 16;
          if (!(k0i <= qrow && k0i >= qrow - W)) p0 = 0.f;
          if (!(k1i <= qrow && k1i >= qrow - W)) p1 = 0.f;
        }
        l_part += p0 + p1;
        P0[r] = (_Float16)p0;
        P1[r] = (_Float16)p1;
      }

#pragma unroll
      for (int dt = 0; dt < 4; ++dt) {
        const unsigned short* vr = &Vs[bufI][(dt * 16 + c) * 40 + g * 4];
        f16x4 va = *(const f16x4*)(vr);
        f16x4 vb = *(const f16x4*)(vr + 16);
        acc[dt] = __builtin_amdgcn_mfma_f32_16x16x16f16(va, P0, acc[dt], 0, 0, 0);
        acc[dt] = __builtin_amdgcn_mfma_f32_16x16x16f16(vb, P1, acc[dt], 0, 0, 0);
      }
    }
    pk = nk; pv = nv;
  }

  float l = l_part;
  l += __shfl_xor(l, 16);
  l += __shfl_xor(l, 32);
  float inv = 1.0f / l;

  unsigned short* ob = y_b + ((size_t)(b * 2048 + r0w + c) * 16 + h) * 64 + g * 4;
#pragma unroll
  for (int dt = 0; dt < 4; ++dt) {
    ushort4 o;
    o.x = f2bf(acc[dt][0] * inv);
    o.y = f2bf(acc[dt][1] * inv);
    o.z = f2bf(acc[dt][2] * inv);
    o.w = f2bf(acc[dt][3] * inv);
    *(ushort4*)(ob + dt * 16) = o;
  }
}

extern "C" void kernel_launch(void* const* d_in, const int* in_sizes, int n_in,
                              void* d_out, int out_size, void* d_ws, size_t ws_size,
                              hipStream_t stream) {
  const float* x = (const float*)d_in[0];
  const float* ve = (const float*)d_in[1];
  const float* cosp = (const float*)d_in[2];
  const float* sinp = (const float*)d_in[3];
  const float* Wq = (const float*)d_in[4];
  const float* Wk = (const float*)d_in[5];
  const float* Wv = (const float*)d_in[6];
  const float* Wproj = (const float*)d_in[7];
  const float* Wgate = (const float*)d_in[8];
  const int* wptr = (const int*)d_in[9];

  unsigned short* xb = (unsigned short*)d_ws;        // 4096x1024 bf16
  unsigned short* wqkv = xb + 4194304;               // 1536x1024 bf16
  unsigned short* wpj = wqkv + 1572864;              // 1024x1024 bf16
  unsigned short* q_r = wpj + 1048576;               // [B,H,T,D] bf16
  unsigned short* k_r = q_r + 4194304;               // [B,Hkv,T,D] bf16
  unsigned short* y_b = k_r + 1048576;               // [B,T,H,D] bf16
  unsigned short* vp2 = y_b + 4194304;               // [B*Hkv][T/32][64][32] fp16
  float* gatep = (float*)(vp2 + 1048576);            // [4096][4] fp32

  cvt_gate<<<6720, 256, 0, stream>>>(x, Wq, Wk, Wv, Wproj, Wgate, xb, wqkv, wpj, gatep);
  gemm_qkv<<<dim3(12, 64), 256, 0, stream>>>(xb, wqkv, cosp, sinp, gatep, ve, q_r, k_r, vp2);
  attn_kernel<<<1024, 256, 0, stream>>>(q_r, k_r, vp2, y_b, wptr);
  gemm_bf16_128<<<dim3(8, 32), 256, 0, stream>>>(y_b, wpj, (float*)d_out, 1024, 1024);
}

// Round 11
// 164.639 us; speedup vs baseline: 1.1547x; 1.0243x over previous
//
#include <hip/hip_runtime.h>

// Shapes (fixed): B=2, T=2048, E=1024, H=16, Hkv=4, D=64, G=4, W=1024
// Scores bounded: q rmsnormed (|q|=8) * 0.125 * k rmsnormed (|k|=8) => |s| <= 8.
// log2(e) folded into q; softmax uses exp2 with FIXED max M = 8*log2(e).
// R11: exact revert to R7 (best measured, 165.8us) + s_setprio(1) around the
// attn MFMA clusters (T5: SIMD hosts 4 waves from 4 DIFFERENT blocks at
// different phases -> role diversity; m191-analog). R10's K-swizzle was
// neutral (T2 regime gate: 2-barrier loop hides LDS-read conflicts).
// Attention: R2 structure: S^T = K·Q^T, 32-key tiles, dbuf LDS, ONE
// barrier/tile, register prefetch, R1 balanced qt remap.
// R7: XCD-aware chunked remap on both GEMMs (T1).
// R6: gemm_bf16 128x128 tile, BK=128 dbuf, 64 MFMA/barrier, 1 block/CU.
// GEMM staging: XOR-swizzled LDS 16B-groups (grp ^ row&7) -> conflict-free
// reads while keeping global_load_lds's wave-uniform-base staging.

typedef float f32x4 __attribute__((ext_vector_type(4)));
typedef short s16x8 __attribute__((ext_vector_type(8)));
typedef short s16x4 __attribute__((ext_vector_type(4)));
typedef _Float16 f16x4 __attribute__((ext_vector_type(4)));

__device__ __forceinline__ unsigned short f2bf(float f) {
  unsigned u = __float_as_uint(f);
  u += 0x7fffu + ((u >> 16) & 1u);   // RNE
  return (unsigned short)(u >> 16);
}
__device__ __forceinline__ unsigned short h16(float f) {
  _Float16 h = (_Float16)f;
  return __builtin_bit_cast(unsigned short, h);
}

__device__ __forceinline__ float fexp2(float x) {
#if __has_builtin(__builtin_amdgcn_exp2f)
  return __builtin_amdgcn_exp2f(x);
#else
  return __expf(x * 0.69314718f);
#endif
}

// async global->LDS, 16B per lane; LDS dest = wave-uniform base + lane*16
__device__ __forceinline__ void gl2lds16(const unsigned short* g, unsigned short* l) {
  __builtin_amdgcn_global_load_lds((const __attribute__((address_space(1))) unsigned int*)g,
                                   (__attribute__((address_space(3))) unsigned int*)l, 16, 0, 0);
}

// ---------------- fp32->bf16 converts + gate, one launch ----------------
__global__ __launch_bounds__(256) void cvt_gate(
    const float* __restrict__ x, const float* __restrict__ wq, const float* __restrict__ wk,
    const float* __restrict__ wv, const float* __restrict__ wp, const float* __restrict__ wgate,
    unsigned short* __restrict__ xb, unsigned short* __restrict__ wqkv,
    unsigned short* __restrict__ wpj, float* __restrict__ gatep) {
  int blk = blockIdx.x;
  if (blk < 6656) {
    int i = blk * 256 + threadIdx.x;  // float4 index, total 1703936
    const float* s;
    unsigned short* d;
    if (i < 1048576) { s = x; d = xb; }
    else if (i < 1310720) { i -= 1048576; s = wq; d = wqkv; }
    else if (i < 1376256) { i -= 1310720; s = wk; d = wqkv + 1048576; }
    else if (i < 1441792) { i -= 1376256; s = wv; d = wqkv + 1310720; }
    else { i -= 1441792; s = wp; d = wpj; }
    float4 v = ((const float4*)s)[i];
    ushort4 o;
    o.x = f2bf(v.x); o.y = f2bf(v.y); o.z = f2bf(v.z); o.w = f2bf(v.w);
    ((ushort4*)d)[i] = o;
  } else {
    int i = (blk - 6656) * 256 + threadIdx.x;  // i = bt*4 + h, total 16384
    int bt = i >> 2, h = i & 3;
    const float4* xp = (const float4*)(x + (size_t)bt * 1024);
    const float4* wpt = (const float4*)(wgate + h * 32);
    float s = 0.f;
#pragma unroll
    for (int j = 0; j < 8; ++j) {
      float4 a = xp[j], b = wpt[j];
      s += a.x * b.x + a.y * b.y + a.z * b.z + a.w * b.w;
    }
    gatep[i] = 2.f / (1.f + __expf(-s));
  }
}

// ---- fused QKV GEMM (64x128 tile, BK=128, swizzled LDS) + RoPE/RMSNorm/gate-ve ----
// A = xb (4096x1024), B = wqkv (1536x1024). Col-tile bn: 0-7 q, 8-9 k, 10-11 v.
// v-epilogue writes vp2 tiled layout directly (transpose_v fused).
__global__ __launch_bounds__(256) void gemm_qkv(
    const unsigned short* __restrict__ A, const unsigned short* __restrict__ B,
    const float* __restrict__ cosp, const float* __restrict__ sinp,
    const float* __restrict__ gatep, const float* __restrict__ ve,
    unsigned short* __restrict__ q_r, unsigned short* __restrict__ k_r,
    unsigned short* __restrict__ vp2) {
  __shared__ unsigned short smem[24576];   // As 64x128 | Bs 128x128; epilogue aliases
  unsigned short* As = smem;               // 8192 elems
  unsigned short* Bs = smem + 8192;        // 16384 elems
  const int K = 1024;
  // R7 XCD chunked remap: 768 blocks, 96/XCD; XCD x gets bm in [8x, 8x+8)
  int lin = blockIdx.y * 12 + blockIdx.x;
  int nl = (lin & 7) * 96 + (lin >> 3);
  int bn = nl % 12, bm = nl / 12;
  int t = threadIdx.x;
  int w = t >> 6, lane = t & 63;
  int c = lane & 15, g = lane >> 4;
  int wm = w >> 1, wn = w & 1;

  f32x4 acc[2][4];
#pragma unroll
  for (int i = 0; i < 2; ++i)
#pragma unroll
    for (int j = 0; j < 4; ++j) acc[i][j] = (f32x4){0.f, 0.f, 0.f, 0.f};

  const unsigned short* Ab = A + (size_t)(bm * 64) * K;
  const unsigned short* Bb = B + (size_t)(bn * 128) * K;
  int srow = lane >> 4;                         // 0..3 (4 rows of 256B per call)
  int sgrp = lane & 15;                         // 16B group within 128-elem row

  for (int k0 = 0; k0 < K; k0 += 128) {
#pragma unroll
    for (int j = 0; j < 4; ++j) {  // A rows w*16 .. +15
      int r0 = w * 16 + j * 4;
      int r = r0 + srow;
      gl2lds16(Ab + (size_t)r * K + k0 + (sgrp ^ (r & 7)) * 8, As + r0 * 128);
    }
#pragma unroll
    for (int j = 0; j < 8; ++j) {  // B rows w*32 .. +31
      int r0 = w * 32 + j * 4;
      int r = r0 + srow;
      gl2lds16(Bb + (size_t)r * K + k0 + (sgrp ^ (r & 7)) * 8, Bs + r0 * 128);
    }
    __syncthreads();
#pragma unroll
    for (int kk = 0; kk < 4; ++kk) {
      int sw = ((kk * 4 + g) ^ (c & 7)) * 8;  // row&7 == c&7 for all tiles
      s16x8 af[2], bf[4];
#pragma unroll
      for (int mt = 0; mt < 2; ++mt)
        af[mt] = *(const s16x8*)(As + (wm * 32 + mt * 16 + c) * 128 + sw);
#pragma unroll
      for (int nt = 0; nt < 4; ++nt)
        bf[nt] = *(const s16x8*)(Bs + (wn * 64 + nt * 16 + c) * 128 + sw);
#pragma unroll
      for (int mt = 0; mt < 2; ++mt)
#pragma unroll
        for (int nt = 0; nt < 4; ++nt)
          acc[mt][nt] = __builtin_amdgcn_mfma_f32_16x16x32_bf16(af[mt], bf[nt], acc[mt][nt], 0, 0, 0);
    }
    __syncthreads();
  }

  // epilogue: lane (c,g) reg r of (mt,nt): local row = wm*32+mt*16+g*4+r,
  // within-head d = nt*16 + c (head = 64 cols = wn half-tile)
  const float QSCL = 0.125f * 1.44269504f;
  if (bn < 10) {  // q/k: rope + rmsnorm -> wave-private LDS transpose -> b128 stores
    unsigned short* eb = smem + w * 2176;  // 32 x 68
#pragma unroll
    for (int mt = 0; mt < 2; ++mt) {
#pragma unroll
      for (int r = 0; r < 4; ++r) {
        int lrow = mt * 16 + g * 4 + r;
        int rowg = bm * 64 + wm * 32 + lrow;
        int tt = rowg & 2047;
        float v0 = acc[mt][0][r], v1 = acc[mt][1][r], v2 = acc[mt][2][r], v3 = acc[mt][3][r];
        float cs0 = cosp[tt * 32 + c], sn0 = sinp[tt * 32 + c];
        float cs1 = cosp[tt * 32 + 16 + c], sn1 = sinp[tt * 32 + 16 + c];
        float r0 = v0 * cs0 + v2 * sn0;
        float r1 = v1 * cs1 + v3 * sn1;
        float r2 = v2 * cs0 - v0 * sn0;
        float r3 = v3 * cs1 - v1 * sn1;
        float ss = r0 * r0 + r1 * r1 + r2 * r2 + r3 * r3;
        ss += __shfl_xor(ss, 1);
        ss += __shfl_xor(ss, 2);
        ss += __shfl_xor(ss, 4);
        ss += __shfl_xor(ss, 8);
        float sc = rsqrtf(ss * (1.0f / 64.0f) + 1.1920929e-07f);
        if (bn < 8) sc *= QSCL;
        eb[lrow * 68 + c] = f2bf(r0 * sc);
        eb[lrow * 68 + 16 + c] = f2bf(r1 * sc);
        eb[lrow * 68 + 32 + c] = f2bf(r2 * sc);
        eb[lrow * 68 + 48 + c] = f2bf(r3 * sc);
      }
    }
    asm volatile("s_waitcnt lgkmcnt(0)" ::: "memory");  // wave-private
#pragma unroll
    for (int j = 0; j < 4; ++j) {
      int idx = lane * 4 + j;  // 256 chunks: 32 rows x 8
      int lrow = idx >> 3;
      int ck = idx & 7;
      s16x8 val = *(const s16x8*)(eb + lrow * 68 + ck * 8);
      int rowg = bm * 64 + wm * 32 + lrow;
      int b = rowg >> 11, tt = rowg & 2047;
      unsigned short* dst;
      if (bn < 8) dst = q_r + ((size_t)(b * 16 + bn * 2 + wn) * 2048 + tt) * 64 + ck * 8;
      else dst = k_r + ((size_t)(b * 4 + (bn - 8) * 2 + wn) * 2048 + tt) * 64 + ck * 8;
      *(s16x8*)dst = val;
    }
  } else {  // v: + gate*ve, transpose to vp2 tiled [s][tile32][d][32keys] fp16
    unsigned short* eb = smem + w * 2560;  // 64 d x 40 (keys padded)
    int h = (bn - 10) * 2 + wn;
#pragma unroll
    for (int mt = 0; mt < 2; ++mt) {
#pragma unroll
      for (int r = 0; r < 4; ++r) {
        int key = mt * 16 + g * 4 + r;               // 0..31 within wave tile
        int rowg = bm * 64 + wm * 32 + key;
        float gate = gatep[rowg * 4 + h];
        const float* vep = ve + (size_t)rowg * 256 + h * 64;
        eb[(0 * 16 + c) * 40 + key] = h16(acc[mt][0][r] + gate * vep[c]);
        eb[(1 * 16 + c) * 40 + key] = h16(acc[mt][1][r] + gate * vep[16 + c]);
        eb[(2 * 16 + c) * 40 + key] = h16(acc[mt][2][r] + gate * vep[32 + c]);
        eb[(3 * 16 + c) * 40 + key] = h16(acc[mt][3][r] + gate * vep[48 + c]);
      }
    }
    asm volatile("s_waitcnt lgkmcnt(0)" ::: "memory");  // wave-private
    int rowg0 = bm * 64 + wm * 32;
    int b = rowg0 >> 11;
    int tile = (rowg0 & 2047) >> 5;
    unsigned short* vb = vp2 + ((size_t)(b * 4 + h) * 64 + tile) * 2048;
#pragma unroll
    for (int j = 0; j < 4; ++j) {
      int cid = j * 64 + lane;  // 256 chunks: 64 d x 4 keygroups
      int d = cid >> 2;
      int kg = cid & 3;
      s16x8 val = *(const s16x8*)(eb + d * 40 + kg * 8);
      *(s16x8*)(vb + d * 32 + kg * 8) = val;
    }
  }
}

// ------- bf16 GEMM 128x128 (m97 structure), BK=128 dbuf, C = A @ B^T -------
// 4 waves, each 64x64 output: 16 MFMA per 8 ds_reads per kk, 64 MFMA/barrier.
// Grid (N/128, M/128) = (8,32) = 256 blocks = exactly 1 block/CU.
__global__ __launch_bounds__(256) void gemm_bf16_128(
    const unsigned short* __restrict__ A, const unsigned short* __restrict__ B,
    float* __restrict__ C, int K, int ldc) {
  __shared__ unsigned short As[2][128 * 128];
  __shared__ unsigned short Bs[2][128 * 128];
  // R7 XCD chunked remap: 256 blocks, 32/XCD; XCD x gets bm in [4x, 4x+4)
  int lin = blockIdx.y * 8 + blockIdx.x;
  int nl = (lin & 7) * 32 + (lin >> 3);
  int bn = nl & 7, bm = nl >> 3;
  int t = threadIdx.x;
  int w = t >> 6, lane = t & 63;
  int c = lane & 15, g = lane >> 4;
  int wm = w >> 1, wn = w & 1;

  f32x4 acc[4][4];
#pragma unroll
  for (int i = 0; i < 4; ++i)
#pragma unroll
    for (int j = 0; j < 4; ++j) acc[i][j] = (f32x4){0.f, 0.f, 0.f, 0.f};

  const unsigned short* Ab = A + (size_t)(bm * 128) * K;
  const unsigned short* Bb = B + (size_t)(bn * 128) * K;
  int srow = lane >> 4;   // 0..3
  int sgrp = lane & 15;   // 16B group within 128-elem row

  // stage K-step k0 into buffer buf: each wave stages its 32 rows of A and B
#define STAGE128(buf, k0)                                                          \
  {                                                                                \
    _Pragma("unroll")                                                              \
    for (int j = 0; j < 8; ++j) {                                                  \
      int r0 = w * 32 + j * 4;                                                     \
      int r = r0 + srow;                                                           \
      gl2lds16(Ab + (size_t)r * K + (k0) + (sgrp ^ (r & 7)) * 8, &As[buf][r0 * 128]); \
      gl2lds16(Bb + (size_t)r * K + (k0) + (sgrp ^ (r & 7)) * 8, &Bs[buf][r0 * 128]); \
    }                                                                              \
  }

  STAGE128(0, 0);
  for (int tstep = 0; tstep < 8; ++tstep) {
    int buf = tstep & 1;
    __syncthreads();  // drains this wave's vmcnt -> buf staged; all waves synced
    if (tstep < 7) STAGE128(buf ^ 1, (tstep + 1) * 128);
#pragma unroll
    for (int kk = 0; kk < 4; ++kk) {
      int sw = ((kk * 4 + g) ^ (c & 7)) * 8;
      s16x8 af[4], bf[4];
#pragma unroll
      for (int mt = 0; mt < 4; ++mt)
        af[mt] = *(const s16x8*)(&As[buf][(wm * 64 + mt * 16 + c) * 128 + sw]);
#pragma unroll
      for (int nt = 0; nt < 4; ++nt)
        bf[nt] = *(const s16x8*)(&Bs[buf][(wn * 64 + nt * 16 + c) * 128 + sw]);
#pragma unroll
      for (int mt = 0; mt < 4; ++mt)
#pragma unroll
        for (int nt = 0; nt < 4; ++nt)
          acc[mt][nt] = __builtin_amdgcn_mfma_f32_16x16x32_bf16(af[mt], bf[nt], acc[mt][nt], 0, 0, 0);
    }
  }
#undef STAGE128

#pragma unroll
  for (int mt = 0; mt < 4; ++mt)
#pragma unroll
    for (int nt = 0; nt < 4; ++nt)
#pragma unroll
      for (int r = 0; r < 4; ++r) {
        int rowg = bm * 128 + wm * 64 + mt * 16 + g * 4 + r;
        int colg = bn * 128 + wn * 64 + nt * 16 + c;
        C[(size_t)rowg * ldc + colg] = acc[mt][nt][r];
      }
}

// ---------------- flash attention: S^T form, dbuf LDS, ONE barrier/tile ----------------
__global__ __launch_bounds__(256) void attn_kernel(
    const unsigned short* __restrict__ q_r, const unsigned short* __restrict__ k_r,
    const unsigned short* __restrict__ v_p2, unsigned short* __restrict__ y_b,
    const int* __restrict__ wptr) {
  const int W = *wptr;
  const int bid = blockIdx.x;
  // Balanced qt remap: co-resident blocks {c, c+256, c+512, c+768} get
  // qt = {m, 15-m, 16+m, 31-m} -> per-CU key-tile count is 102 for every m.
  const int rr = bid >> 8, cc = bid & 255;
  const int mm = cc & 7;
  const int h = (cc >> 3) & 15, b = cc >> 7;
  const int qt = (rr == 0) ? mm : (rr == 1) ? 15 - mm : (rr == 2) ? 16 + mm : 31 - mm;
  const int tid = threadIdx.x;
  const int w = tid >> 6, lane = tid & 63, c = lane & 15, g = lane >> 4;
  const int r0b = qt * 64;
  const int r0w = r0b + w * 16;
  const int hkv = h >> 2;
  const float M = 11.5415603f;  // 8 * log2(e)

  __shared__ unsigned short Ks[2][32 * 68];
  __shared__ unsigned short Vs[2][64 * 40];

  const unsigned short* kbase = k_r + (size_t)(b * 4 + hkv) * 131072;
  const unsigned short* vbase = v_p2 + (size_t)(b * 4 + hkv) * 131072;
  const unsigned short* qbase = q_r + ((size_t)(b * 16 + h) * 2048 + r0w) * 64;

  s16x8 q_lo = *(const s16x8*)(qbase + c * 64 + g * 8);
  s16x8 q_hi = *(const s16x8*)(qbase + c * 64 + 32 + g * 8);

  int kt0w = r0w - W; if (kt0w < 0) kt0w = 0;
  const int ktEw = r0w + 16;
  int KT0 = r0b - W; if (KT0 < 0) KT0 = 0;
  KT0 &= ~31;
  const int KTE = r0b + 64;

  float l_part = 0.f;
  f32x4 acc[4];
#pragma unroll
  for (int dt = 0; dt < 4; ++dt) acc[dt] = (f32x4){0.f, 0.f, 0.f, 0.f};

  s16x8 pk = *(const s16x8*)(kbase + (size_t)KT0 * 64 + tid * 8);
  s16x8 pv = *(const s16x8*)(vbase + (size_t)(KT0 >> 5) * 2048 + tid * 8);

  const int koff = (tid >> 3) * 68 + (tid & 7) * 8;
  const int voff = (tid >> 2) * 40 + (tid & 3) * 8;

  int bufI = 0;
  for (int kt = KT0; kt < KTE; kt += 32, bufI ^= 1) {
    int nkt = (kt + 32 < KTE) ? kt + 32 : kt;
    s16x8 nk = *(const s16x8*)(kbase + (size_t)nkt * 64 + tid * 8);
    s16x8 nv = *(const s16x8*)(vbase + (size_t)(nkt >> 5) * 2048 + tid * 8);

    // stage into buf bufI (other buffer may still be read by lagging waves - safe)
    unsigned short* kdst = &Ks[bufI][koff];
    *(s16x4*)kdst = __builtin_shufflevector(pk, pk, 0, 1, 2, 3);
    *(s16x4*)(kdst + 4) = __builtin_shufflevector(pk, pk, 4, 5, 6, 7);
    *(s16x8*)(&Vs[bufI][voff]) = pv;
    __syncthreads();  // the ONLY barrier per tile

    if (kt + 32 > kt0w && kt < ktEw) {
      const unsigned short* kr0 = &Ks[bufI][c * 68 + g * 8];
      s16x4 a0 = *(const s16x4*)(kr0);
      s16x4 a1 = *(const s16x4*)(kr0 + 4);
      s16x4 a2 = *(const s16x4*)(kr0 + 32);
      s16x4 a3 = *(const s16x4*)(kr0 + 36);
      const unsigned short* kr1 = kr0 + 16 * 68;
      s16x4 a4 = *(const s16x4*)(kr1);
      s16x4 a5 = *(const s16x4*)(kr1 + 4);
      s16x4 a6 = *(const s16x4*)(kr1 + 32);
      s16x4 a7 = *(const s16x4*)(kr1 + 36);
      s16x8 k0lo = __builtin_shufflevector(a0, a1, 0, 1, 2, 3, 4, 5, 6, 7);
      s16x8 k0hi = __builtin_shufflevector(a2, a3, 0, 1, 2, 3, 4, 5, 6, 7);
      s16x8 k1lo = __builtin_shufflevector(a4, a5, 0, 1, 2, 3, 4, 5, 6, 7);
      s16x8 k1hi = __builtin_shufflevector(a6, a7, 0, 1, 2, 3, 4, 5, 6, 7);

      f32x4 S0 = (f32x4){0.f, 0.f, 0.f, 0.f};
      f32x4 S1 = (f32x4){0.f, 0.f, 0.f, 0.f};
      __builtin_amdgcn_s_setprio(1);  // T5: favor MFMA-phase wave on the SIMD
      S0 = __builtin_amdgcn_mfma_f32_16x16x32_bf16(k0lo, q_lo, S0, 0, 0, 0);
      S0 = __builtin_amdgcn_mfma_f32_16x16x32_bf16(k0hi, q_hi, S0, 0, 0, 0);
      S1 = __builtin_amdgcn_mfma_f32_16x16x32_bf16(k1lo, q_lo, S1, 0, 0, 0);
      S1 = __builtin_amdgcn_mfma_f32_16x16x32_bf16(k1hi, q_hi, S1, 0, 0, 0);
      __builtin_amdgcn_s_setprio(0);

      f16x4 P0, P1;
      const bool edge = (kt < kt0w + 32) || (kt + 32 > r0w);
      const int qrow = r0w + c;
#pragma unroll
      for (int r = 0; r < 4; ++r) {
        float p0 = fexp2(S0[r] - M);
        float p1 = fexp2(S1[r] - M);
        if (edge) {
          int k0i = kt + g * 4 + r;
          int k1i = k0i + 16;
          if (!(k0i <= qrow && k0i >= qrow - W)) p0 = 0.f;
          if (!(k1i <= qrow && k1i >= qrow - W)) p1 = 0.f;
        }
        l_part += p0 + p1;
        P0[r] = (_Float16)p0;
        P1[r] = (_Float16)p1;
      }

      __builtin_amdgcn_s_setprio(1);  // T5: PV MFMA cluster
#pragma unroll
      for (int dt = 0; dt < 4; ++dt) {
        const unsigned short* vr = &Vs[bufI][(dt * 16 + c) * 40 + g * 4];
        f16x4 va = *(const f16x4*)(vr);
        f16x4 vb = *(const f16x4*)(vr + 16);
        acc[dt] = __builtin_amdgcn_mfma_f32_16x16x16f16(va, P0, acc[dt], 0, 0, 0);
        acc[dt] = __builtin_amdgcn_mfma_f32_16x16x16f16(vb, P1, acc[dt], 0, 0, 0);
      }
      __builtin_amdgcn_s_setprio(0);
    }
    pk = nk; pv = nv;
  }

  float l = l_part;
  l += __shfl_xor(l, 16);
  l += __shfl_xor(l, 32);
  float inv = 1.0f / l;

  unsigned short* ob = y_b + ((size_t)(b * 2048 + r0w + c) * 16 + h) * 64 + g * 4;
#pragma unroll
  for (int dt = 0; dt < 4; ++dt) {
    ushort4 o;
    o.x = f2bf(acc[dt][0] * inv);
    o.y = f2bf(acc[dt][1] * inv);
    o.z = f2bf(acc[dt][2] * inv);
    o.w = f2bf(acc[dt][3] * inv);
    *(ushort4*)(ob + dt * 16) = o;
  }
}

extern "C" void kernel_launch(void* const* d_in, const int* in_sizes, int n_in,
                              void* d_out, int out_size, void* d_ws, size_t ws_size,
                              hipStream_t stream) {
  const float* x = (const float*)d_in[0];
  const float* ve = (const float*)d_in[1];
  const float* cosp = (const float*)d_in[2];
  const float* sinp = (const float*)d_in[3];
  const float* Wq = (const float*)d_in[4];
  const float* Wk = (const float*)d_in[5];
  const float* Wv = (const float*)d_in[6];
  const float* Wproj = (const float*)d_in[7];
  const float* Wgate = (const float*)d_in[8];
  const int* wptr = (const int*)d_in[9];

  unsigned short* xb = (unsigned short*)d_ws;        // 4096x1024 bf16
  unsigned short* wqkv = xb + 4194304;               // 1536x1024 bf16
  unsigned short* wpj = wqkv + 1572864;              // 1024x1024 bf16
  unsigned short* q_r = wpj + 1048576;               // [B,H,T,D] bf16
  unsigned short* k_r = q_r + 4194304;               // [B,Hkv,T,D] bf16
  unsigned short* y_b = k_r + 1048576;               // [B,T,H,D] bf16
  unsigned short* vp2 = y_b + 4194304;               // [B*Hkv][T/32][64][32] fp16
  float* gatep = (float*)(vp2 + 1048576);            // [4096][4] fp32

  cvt_gate<<<6720, 256, 0, stream>>>(x, Wq, Wk, Wv, Wproj, Wgate, xb, wqkv, wpj, gatep);
  gemm_qkv<<<dim3(12, 64), 256, 0, stream>>>(xb, wqkv, cosp, sinp, gatep, ve, q_r, k_r, vp2);
  attn_kernel<<<1024, 256, 0, stream>>>(q_r, k_r, vp2, y_b, wptr);
  gemm_bf16_128<<<dim3(8, 32), 256, 0, stream>>>(y_b, wpj, (float*)d_out, 1024, 1024);
}